// Round 10
// baseline (400.587 us; speedup 1.0000x reference)
//
#include <hip/hip_runtime.h>
#include <hip/hip_bf16.h>

// BranchingQNetwork fused forward for MI355X (gfx950).
// B=32, N=2048, OBS=256, HID=128, n1=n2=8.
// v10: attn reverted EXACTLY to v7 (proven: shfl_xor reductions, shfl
// P-redistribute). fused_pp kept (q-store fixed: 32 cols/thread).
// Single unproven component (fused_pp) for decisive attribution.

typedef __attribute__((ext_vector_type(4))) float f32x4;
typedef __attribute__((ext_vector_type(8))) short bf16x8;
typedef __attribute__((ext_vector_type(4))) unsigned int u32x4;

#define LOG2E 1.44269504088896340736f
#define NEGC 9.0e15f

static __device__ __forceinline__ unsigned short f2bf(float f) {
  unsigned int x = __builtin_bit_cast(unsigned int, f);
  unsigned int r = (x + 0x7fffu + ((x >> 16) & 1u)) >> 16;   // RNE
  return (unsigned short)r;
}
static __device__ __forceinline__ float bf2f(unsigned short u) {
  return __builtin_bit_cast(float, ((unsigned int)u) << 16);
}
static __device__ __forceinline__ unsigned int pack2bf(float lo, float hi) {
  return (unsigned int)f2bf(lo) | ((unsigned int)f2bf(hi) << 16);
}
static __device__ __forceinline__ f32x4 mfma16(bf16x8 a, bf16x8 b, f32x4 c) {
  return __builtin_amdgcn_mfma_f32_16x16x32_bf16(a, b, c, 0, 0, 0);
}

// ---------------------------------------------------------------------------
// Kernel 0: weight prep into FRAG-LINEAR layouts.
// ---------------------------------------------------------------------------
__global__ __launch_bounds__(256) void prep_kernel(
    const float* __restrict__ Wv, const float* __restrict__ Wk,
    const float* __restrict__ Wq, const float* __restrict__ Wout,
    unsigned short* __restrict__ Wf_hi, unsigned short* __restrict__ Wf_lo,
    unsigned short* __restrict__ WoutT) {
  int gid = blockIdx.x * 256 + threadIdx.x;
  if (gid < 12288) {                 // (kc, t, lane)
    int kc = gid / 1536;
    int rem = gid - kc * 1536;
    int t = rem >> 6, lane = rem & 63;
    int hf = lane & 15, qf = lane >> 4;
    int sec = t >> 3;
    int j = (t & 7) * 16 + hf;
    const float* W = (sec == 0) ? Wq : (sec == 1) ? Wk : Wv;
#pragma unroll
    for (int e = 0; e < 8; ++e) {
      int k = kc * 32 + qf * 8 + e;
      float w = W[k * 128 + j];
      unsigned short hi = f2bf(w);
      Wf_hi[gid * 8 + e] = hi;
      Wf_lo[gid * 8 + e] = f2bf(w - bf2f(hi));
    }
  } else if (gid < 12288 + 16384) {
    int i2 = gid - 12288;
    int j = i2 >> 7, c = i2 & 127;
    WoutT[i2] = f2bf(Wout[c * 128 + j]);
  }
}

// ---------------------------------------------------------------------------
// Kernel 1: FUSED proj + mask-prepack. 3072 blocks x 256 threads, 2 blocks/CU.
// role = bid%3: 0 -> proj (1024 blocks, 4 waves, 64 rows each);
//               1,2 -> prepack (2048 blocks, 4 waves x 8 mask rows each).
// ---------------------------------------------------------------------------
__global__ __launch_bounds__(256, 2) void fused_pp_kernel(
    const float* __restrict__ x,
    const unsigned short* __restrict__ Wf_hi, const unsigned short* __restrict__ Wf_lo,
    const float* __restrict__ bq, const float* __restrict__ bk, const float* __restrict__ bv,
    unsigned short* __restrict__ q_bf, unsigned short* __restrict__ Kf,
    unsigned short* __restrict__ Vf,
    const float* __restrict__ mask, unsigned long long* __restrict__ bits) {
  __shared__ bf16x8 wst_hi[1536];              // 24 KB
  __shared__ bf16x8 wst_lo[1536];              // 24 KB
  __shared__ unsigned short vbuf[9216];        // 18 KB (max of [64][136], [128][72])

  const int tid = threadIdx.x;
  const int lane = tid & 63, wid = tid >> 6;
  const int bid = blockIdx.x;
  const int role = bid % 3;

  if (role != 0) {
    // ---------------- prepack role ----------------
    const int pidx = (bid / 3) * 2 + (role - 1);   // 0..2047
    const int gwave = pidx * 4 + wid;              // 0..8191
    const int T = lane & 3;
    const int sh = T << 4;
    for (int r = 0; r < 8; ++r) {
      const long row = (long)gwave * 8 + r;
      const float* mp = mask + row * 2048;
      unsigned long long* op = bits + row * 32;
#pragma unroll
      for (int g = 0; g < 8; ++g) {
        f32x4 v = *(const f32x4*)(mp + g * 256 + lane * 4);
        unsigned long long b0 = __ballot(v[0] != 0.0f);
        unsigned long long b1 = __ballot(v[1] != 0.0f);
        unsigned long long b2 = __ballot(v[2] != 0.0f);
        unsigned long long b3 = __ballot(v[3] != 0.0f);
        unsigned long long f0 = (b0 >> sh) & 0xFFFFull;
        unsigned long long f1 = (b1 >> sh) & 0xFFFFull;
        unsigned long long f2 = (b2 >> sh) & 0xFFFFull;
        unsigned long long f3 = (b3 >> sh) & 0xFFFFull;
        unsigned long long val = f0 | (f1 << 16) | (f2 << 32) | (f3 << 48);
        if (lane < 4) op[g * 4 + T] = val;
      }
    }
    return;
  }

  // ---------------- proj role ----------------
  const int pb = bid / 3;                        // 0..1023
  const long rbase = (long)pb * 64;
  const int qq = lane >> 4, hh = lane & 15;
  const long rowA = rbase + wid * 16 + hh;
  const f32x4 zero4 = {0.f, 0.f, 0.f, 0.f};
  f32x4 acc[24];
#pragma unroll
  for (int t = 0; t < 24; ++t) acc[t] = zero4;

  for (int kc = 0; kc < 8; ++kc) {
    __syncthreads();
#pragma unroll
    for (int i = 0; i < 6; ++i) {
      int idx = i * 256 + tid;
      wst_hi[idx] = *(const bf16x8*)(Wf_hi + ((long)kc * 1536 + idx) * 8);
      wst_lo[idx] = *(const bf16x8*)(Wf_lo + ((long)kc * 1536 + idx) * 8);
    }
    __syncthreads();

    const float* xp = x + rowA * 256 + kc * 32 + qq * 8;
    f32x4 x0 = *(const f32x4*)xp;
    f32x4 x1 = *(const f32x4*)(xp + 4);
    bf16x8 ah, al;
#pragma unroll
    for (int j = 0; j < 8; ++j) {
      float f = (j < 4) ? x0[j] : x1[j - 4];
      unsigned short h = f2bf(f);
      ah[j] = (short)h;
      al[j] = (short)f2bf(f - bf2f(h));
    }
#pragma unroll
    for (int t = 0; t < 24; ++t) {
      bf16x8 bh = wst_hi[t * 64 + lane];
      bf16x8 bl = wst_lo[t * 64 + lane];
      acc[t] = mfma16(ah, bh, acc[t]);
      acc[t] = mfma16(al, bh, acc[t]);
      acc[t] = mfma16(ah, bl, acc[t]);
    }
  }

  const int rowL = wid * 16 + qq * 4;            // 0..63
  const int b = (int)(rbase >> 11);
  const int tbase = (int)((rbase & 2047) >> 6);  // one kv-tile per block

  for (int sec = 0; sec < 3; ++sec) {
    __syncthreads();
#pragma unroll
    for (int tp = 0; tp < 8; ++tp) {
      const int t = sec * 8 + tp;
      const int j = tp * 16 + hh;
      const float bias = (sec == 0) ? bq[j] : (sec == 1) ? bk[j] : bv[j];
#pragma unroll
      for (int r = 0; r < 4; ++r) {
        unsigned short h = f2bf(fmaxf(acc[t][r] + bias, 0.f));
        if (sec == 2) vbuf[j * 72 + rowL + r] = h;        // V transposed [h][n]
        else          vbuf[(rowL + r) * 136 + j] = h;
      }
    }
    __syncthreads();
    if (sec == 0) {
      // q: row-major coalesced store (64 rows x 128 cols; 32 cols/thread)
      const int row = tid >> 2, ch = tid & 3;
      bf16x8 w1 = *(const bf16x8*)&vbuf[row * 136 + ch * 32];
      bf16x8 w2 = *(const bf16x8*)&vbuf[row * 136 + ch * 32 + 8];
      bf16x8 w3 = *(const bf16x8*)&vbuf[row * 136 + ch * 32 + 16];
      bf16x8 w4 = *(const bf16x8*)&vbuf[row * 136 + ch * 32 + 24];
      unsigned short* op = q_bf + (rbase + row) * 128 + ch * 32;
      *(bf16x8*)op = w1;
      *(bf16x8*)(op + 8) = w2;
      *(bf16x8*)(op + 16) = w3;
      *(bf16x8*)(op + 24) = w4;
    } else if (sec == 1) {
      // k -> Kf frag order (one tile: 16 segs x 64 lanes)
#pragma unroll
      for (int it = 0; it < 4; ++it) {
        int gid = it * 256 + tid;                  // (seg, lane)
        int seg = gid >> 6, ln = gid & 63;         // seg = m*4+kc
        int m = seg >> 2, kc = seg & 3;
        int hf = ln & 15, qf = ln >> 4;
        bf16x8 w = *(const bf16x8*)&vbuf[(m * 16 + hf) * 136 + kc * 32 + qf * 8];
        long off = (((long)(b * 32 + tbase) * 16 + seg) * 64 + ln) * 8;
        *(bf16x8*)(Kf + off) = w;
      }
    } else {
      // v -> Vf frag order (from transposed vbuf[h][n])
#pragma unroll
      for (int it = 0; it < 4; ++it) {
        int gid = it * 256 + tid;                  // (seg, lane)
        int seg = gid >> 6, ln = gid & 63;         // seg = ht*2+c
        int ht = seg >> 1, c = seg & 1;
        int hf = ln & 15, qf = ln >> 4;
        bf16x8 w = *(const bf16x8*)&vbuf[(ht * 16 + hf) * 72 + c * 32 + qf * 8];
        long off = (((long)(b * 32 + tbase) * 16 + seg) * 64 + ln) * 8;
        *(bf16x8*)(Vf + off) = w;
      }
    }
  }
}

// ---------------------------------------------------------------------------
// Kernel 2: flash attention — EXACT v7 (proven passing at 349us).
// 512 blocks x 256 threads (4 waves x 32 q-rows), 2 blocks/CU.
// Single barrier/tile, write-early double-buffer, setprio, defer-max THR=8,
// shfl_xor softmax reductions, shfl P-redistribute.
// ---------------------------------------------------------------------------
__global__ __launch_bounds__(256, 2) void attn_kernel(
    const unsigned short* __restrict__ q_bf, const unsigned short* __restrict__ Kf,
    const unsigned short* __restrict__ Vf,
    const unsigned long long* __restrict__ bits, unsigned short* __restrict__ out_att) {
  __shared__ bf16x8 kls[2][1024];   // 2 x 16 KB
  __shared__ bf16x8 vls[2][1024];   // 2 x 16 KB

  const int tid = threadIdx.x;
  const int lane = tid & 63, wid = tid >> 6;
  const int qq = lane >> 4, hh = lane & 15;
  const int orig = blockIdx.x;
  const int b = ((orig & 7) << 2) | ((orig >> 3) & 3);   // XCD-clustered batches
  const int nb = orig >> 5;                              // 0..15
  const long qbase = (long)b * 2048 + nb * 128 + wid * 32;

  const f32x4 zero4 = {0.f, 0.f, 0.f, 0.f};

  bf16x8 qh[2][4];
#pragma unroll
  for (int ctq = 0; ctq < 2; ++ctq)
#pragma unroll
    for (int kc = 0; kc < 4; ++kc)
      qh[ctq][kc] = *(const bf16x8*)(q_bf + (qbase + ctq * 16 + hh) * 128 + kc * 32 + qq * 8);

  const unsigned long long* br0 = bits + (qbase + hh) * 32;
  const unsigned long long* br1 = bits + (qbase + 16 + hh) * 32;
  const unsigned short* kf0 = Kf + (long)(b * 32) * 8192;
  const unsigned short* vf0 = Vf + (long)(b * 32) * 8192;

  f32x4 o_acc[8][2];
#pragma unroll
  for (int ht = 0; ht < 8; ++ht) { o_acc[ht][0] = zero4; o_acc[ht][1] = zero4; }
  float m_run[2] = {-3.0e38f, -3.0e38f};
  float l_run[2] = {0.f, 0.f};

  // staging: wave wid owns segments wid*8 .. wid*8+7 (seg<16: K, else V)
  bf16x8 stg[8];
  const int seg0 = wid * 8;
  auto LOADREG = [&](int t) {
#pragma unroll
    for (int i = 0; i < 8; ++i) {
      int seg = seg0 + i;
      const unsigned short* src = (seg < 16)
          ? kf0 + (long)t * 8192 + (seg * 64 + lane) * 8
          : vf0 + (long)t * 8192 + ((seg - 16) * 64 + lane) * 8;
      stg[i] = *(const bf16x8*)src;
    }
  };
  auto WRITEBUF = [&](int nb2) {
#pragma unroll
    for (int i = 0; i < 8; ++i) {
      int seg = seg0 + i;
      if (seg < 16) kls[nb2][seg * 64 + lane] = stg[i];
      else          vls[nb2][(seg - 16) * 64 + lane] = stg[i];
    }
  };

  LOADREG(0);
  WRITEBUF(0);
  LOADREG(1);
  __syncthreads();

  unsigned long long bc0 = br0[0];
  unsigned long long bc1 = br1[0];

  const int src0 = (((qq << 1)) & 3) * 16 + hh;
  const int src1 = (((qq << 1) + 1) & 3) * 16 + hh;
  const bool hiq = qq >= 2;
  int cur = 0;

  for (int t = 0; t < 32; ++t) {
    unsigned long long bn0 = 0, bn1 = 0;
    if (t + 1 < 32) { bn0 = br0[t + 1]; bn1 = br1[t + 1]; }

    // next-tile staging issued BEFORE compute
    if (t + 1 < 32) WRITEBUF(cur ^ 1);
    if (t + 2 < 32) LOADREG(t + 2);

    // S^T = K·Q^T from LDS (conflict-free lane*16 reads)
    f32x4 s[2][4];
#pragma unroll
    for (int m = 0; m < 4; ++m) { s[0][m] = zero4; s[1][m] = zero4; }
    __builtin_amdgcn_s_setprio(1);
#pragma unroll
    for (int m = 0; m < 4; ++m) {
      bf16x8 khf[4];
#pragma unroll
      for (int kc = 0; kc < 4; ++kc) khf[kc] = kls[cur][(m * 4 + kc) * 64 + lane];
#pragma unroll
      for (int kc = 0; kc < 4; ++kc)
#pragma unroll
        for (int ctq = 0; ctq < 2; ++ctq)
          s[ctq][m] = mfma16(khf[kc], qh[ctq][kc], s[ctq][m]);
    }
    __builtin_amdgcn_s_setprio(0);

    // bitmask select; bit layout: (bc >> qq) bit (r*16 + m*4)
    {
      const unsigned long long bb0 = bc0 >> qq;
      const unsigned long long bb1 = bc1 >> qq;
#pragma unroll
      for (int m = 0; m < 4; ++m)
#pragma unroll
        for (int r = 0; r < 4; ++r) {
          const int sh = r * 16 + m * 4;
          s[0][m][r] = ((bb0 >> sh) & 1ull) ? s[0][m][r] : -NEGC;
          s[1][m][r] = ((bb1 >> sh) & 1ull) ? s[1][m][r] : -NEGC;
        }
    }

    // fp32 online softmax, threshold defer-max (exact: P <= e^8)
    unsigned int pk[2][4][2];
#pragma unroll
    for (int ctq = 0; ctq < 2; ++ctq) {
      float mx = s[ctq][0][0];
#pragma unroll
      for (int m = 0; m < 4; ++m)
#pragma unroll
        for (int r = 0; r < 4; ++r) mx = fmaxf(mx, s[ctq][m][r]);
      mx = fmaxf(mx, __shfl_xor(mx, 16, 64));
      mx = fmaxf(mx, __shfl_xor(mx, 32, 64));
      if (__any(mx > m_run[ctq] + 8.0f)) {
        float mnew = fmaxf(m_run[ctq], mx);
        float sc = exp2f((m_run[ctq] - mnew) * LOG2E);
        m_run[ctq] = mnew;
        l_run[ctq] *= sc;
#pragma unroll
        for (int ht = 0; ht < 8; ++ht) o_acc[ht][ctq] *= sc;
      }
      float ps = 0.f;
#pragma unroll
      for (int m = 0; m < 4; ++m)
#pragma unroll
        for (int r = 0; r < 4; ++r) {
          float p = exp2f((s[ctq][m][r] - m_run[ctq]) * LOG2E);
          s[ctq][m][r] = p;
          ps += p;
        }
      ps += __shfl_xor(ps, 16, 64);
      ps += __shfl_xor(ps, 32, 64);
      l_run[ctq] += ps;
#pragma unroll
      for (int m = 0; m < 4; ++m) {
        pk[ctq][m][0] = pack2bf(s[ctq][m][0], s[ctq][m][1]);
        pk[ctq][m][1] = pack2bf(s[ctq][m][2], s[ctq][m][3]);
      }
    }

    // redistribute P (C layout) -> B-frag layout via shfl (proven)
    bf16x8 pb[2][2];
#pragma unroll
    for (int ctq = 0; ctq < 2; ++ctq)
#pragma unroll
      for (int c = 0; c < 2; ++c) {
        unsigned int a0 = (unsigned int)__shfl((int)pk[ctq][2 * c][0], src0, 64);
        unsigned int a1 = (unsigned int)__shfl((int)pk[ctq][2 * c][1], src0, 64);
        unsigned int a2 = (unsigned int)__shfl((int)pk[ctq][2 * c][0], src1, 64);
        unsigned int a3 = (unsigned int)__shfl((int)pk[ctq][2 * c][1], src1, 64);
        unsigned int b0 = (unsigned int)__shfl((int)pk[ctq][2 * c + 1][0], src0, 64);
        unsigned int b1 = (unsigned int)__shfl((int)pk[ctq][2 * c + 1][1], src0, 64);
        unsigned int b2 = (unsigned int)__shfl((int)pk[ctq][2 * c + 1][0], src1, 64);
        unsigned int b3 = (unsigned int)__shfl((int)pk[ctq][2 * c + 1][1], src1, 64);
        u32x4 w;
        w[0] = hiq ? b0 : a0;
        w[1] = hiq ? b1 : a1;
        w[2] = hiq ? b2 : a2;
        w[3] = hiq ? b3 : a3;
        pb[ctq][c] = __builtin_bit_cast(bf16x8, w);
      }

    // O^T += V^T · P from LDS
    __builtin_amdgcn_s_setprio(1);
#pragma unroll
    for (int ht = 0; ht < 8; ++ht)
#pragma unroll
      for (int c = 0; c < 2; ++c) {
        bf16x8 vf = vls[cur][(ht * 2 + c) * 64 + lane];
#pragma unroll
        for (int ctq = 0; ctq < 2; ++ctq)
          o_acc[ht][ctq] = mfma16(vf, pb[ctq][c], o_acc[ht][ctq]);
      }
    __builtin_amdgcn_s_setprio(0);

    __syncthreads();   // single barrier per tile
    cur ^= 1;
    bc0 = bn0;
    bc1 = bn1;
  }

  // epilogue: normalize, store bf16. O^T frag: row h = ht*16+qq*4+r, col q=hh.
#pragma unroll
  for (int ctq = 0; ctq < 2; ++ctq) {
    float inv = 1.0f / l_run[ctq];
    const long row = qbase + ctq * 16 + hh;
#pragma unroll
    for (int ht = 0; ht < 8; ++ht) {
      f32x4 o = o_acc[ht][ctq];
      uint2 w;
      w.x = pack2bf(o[0] * inv, o[1] * inv);
      w.y = pack2bf(o[2] * inv, o[3] * inv);
      *(uint2*)(out_att + row * 128 + ht * 16 + qq * 4) = w;
    }
  }
}

// ---------------------------------------------------------------------------
// Kernel 3: out = relu(out_att @ Wout + bout) fused with the three heads.
// ---------------------------------------------------------------------------
__global__ __launch_bounds__(256) void wout_heads_kernel(
    const unsigned short* __restrict__ out_att, const unsigned short* __restrict__ WoutT,
    const float* __restrict__ bout,
    const float* __restrict__ Wval, const float* __restrict__ bval,
    const float* __restrict__ Wadv1, const float* __restrict__ badv1,
    const float* __restrict__ Wadv2, const float* __restrict__ badv2,
    float* __restrict__ value, float* __restrict__ adv1, float* __restrict__ adv2) {
  const int lane = threadIdx.x & 63, wid = threadIdx.x >> 6;
  const int qq = lane >> 4, hh = lane & 15;
  const long rowA = (long)blockIdx.x * 64 + wid * 16 + hh;
  const f32x4 zero4 = {0.f, 0.f, 0.f, 0.f};
  f32x4 acc[8];
#pragma unroll
  for (int t = 0; t < 8; ++t) acc[t] = zero4;
#pragma unroll
  for (int kc = 0; kc < 4; ++kc) {
    bf16x8 af = *(const bf16x8*)(out_att + rowA * 128 + kc * 32 + qq * 8);
#pragma unroll
    for (int t = 0; t < 8; ++t) {
      bf16x8 bf = *(const bf16x8*)(WoutT + (t * 16 + hh) * 128 + kc * 32 + qq * 8);
      acc[t] = mfma16(af, bf, acc[t]);
    }
  }
  float pv[4] = {0.f, 0.f, 0.f, 0.f};
  float pa1[4][8], pa2[4][8];
#pragma unroll
  for (int r = 0; r < 4; ++r)
#pragma unroll
    for (int j = 0; j < 8; ++j) { pa1[r][j] = 0.f; pa2[r][j] = 0.f; }
#pragma unroll
  for (int t = 0; t < 8; ++t) {
    const int col = t * 16 + hh;
    const float bo = bout[col];
    const float wv = Wval[col];
    const f32x4 w1a = *(const f32x4*)(Wadv1 + col * 8);
    const f32x4 w1b = *(const f32x4*)(Wadv1 + col * 8 + 4);
    const f32x4 w2a = *(const f32x4*)(Wadv2 + col * 8);
    const f32x4 w2b = *(const f32x4*)(Wadv2 + col * 8 + 4);
#pragma unroll
    for (int r = 0; r < 4; ++r) {
      float h = fmaxf(acc[t][r] + bo, 0.f);
      pv[r] += h * wv;
#pragma unroll
      for (int j = 0; j < 4; ++j) {
        pa1[r][j]     += h * w1a[j];
        pa1[r][4 + j] += h * w1b[j];
        pa2[r][j]     += h * w2a[j];
        pa2[r][4 + j] += h * w2b[j];
      }
    }
  }
#pragma unroll
  for (int r = 0; r < 4; ++r) {
#pragma unroll
    for (int s = 1; s < 16; s <<= 1) {
      pv[r] += __shfl_xor(pv[r], s, 64);
#pragma unroll
      for (int j = 0; j < 8; ++j) {
        pa1[r][j] += __shfl_xor(pa1[r][j], s, 64);
        pa2[r][j] += __shfl_xor(pa2[r][j], s, 64);
      }
    }
  }
  if (hh == 0) {
    const float bv0 = bval[0];
#pragma unroll
    for (int r = 0; r < 4; ++r) {
      const long row = (long)blockIdx.x * 64 + wid * 16 + qq * 4 + r;
      value[row] = pv[r] + bv0;
#pragma unroll
      for (int j = 0; j < 8; ++j) {
        adv1[row * 8 + j] = pa1[r][j] + badv1[j];
        adv2[row * 8 + j] = pa2[r][j] + badv2[j];
      }
    }
  }
}

// ---------------------------------------------------------------------------
// Kernel 4: per-batch column sums of adv1/adv2 over N (deterministic tree).
// ---------------------------------------------------------------------------
__global__ __launch_bounds__(256) void sums_kernel(const float* __restrict__ adv1,
                                                   const float* __restrict__ adv2,
                                                   float* __restrict__ sums) {
  const int b = blockIdx.x, tid = threadIdx.x;
  __shared__ float red[4][16];
  float p[16];
#pragma unroll
  for (int j = 0; j < 16; ++j) p[j] = 0.f;
  for (int n = tid; n < 2048; n += 256) {
    const long row = (long)b * 2048 + n;
    const f32x4 a1a = *(const f32x4*)(adv1 + row * 8);
    const f32x4 a1b = *(const f32x4*)(adv1 + row * 8 + 4);
    const f32x4 a2a = *(const f32x4*)(adv2 + row * 8);
    const f32x4 a2b = *(const f32x4*)(adv2 + row * 8 + 4);
#pragma unroll
    for (int j = 0; j < 4; ++j) {
      p[j] += a1a[j]; p[4 + j] += a1b[j];
      p[8 + j] += a2a[j]; p[12 + j] += a2b[j];
    }
  }
#pragma unroll
  for (int s = 1; s < 64; s <<= 1)
#pragma unroll
    for (int j = 0; j < 16; ++j) p[j] += __shfl_xor(p[j], s, 64);
  const int wid = tid >> 6;
  if ((tid & 63) == 0)
#pragma unroll
    for (int j = 0; j < 16; ++j) red[wid][j] = p[j];
  __syncthreads();
  if (tid < 16)
    sums[b * 16 + tid] = red[0][tid] + red[1][tid] + red[2][tid] + red[3][tid];
}

// ---------------------------------------------------------------------------
// Kernel 5: q1/q2 = value + adv - mean(adv). Output: [q1 | q2] fp32 flat.
// ---------------------------------------------------------------------------
__global__ void combine_kernel(const float* __restrict__ value, const float* __restrict__ adv1,
                               const float* __restrict__ adv2, const float* __restrict__ sums,
                               float* __restrict__ out) {
  const int idx = blockIdx.x * 256 + threadIdx.x;   // 0 .. 1048575
  const int half = 524288;
  const int which = (idx >= half) ? 1 : 0;
  const int rem = idx - which * half;
  const int b = rem >> 14;
  const int r2 = rem & 16383;
  const int n = r2 >> 3, j = r2 & 7;
  const long row = (long)b * 2048 + n;
  const float* adv = which ? adv2 : adv1;
  const float mean = sums[b * 16 + which * 8 + j] * (1.0f / 2048.0f);
  out[idx] = value[row] + adv[row * 8 + j] - mean;
}

// ---------------------------------------------------------------------------
extern "C" void kernel_launch(void* const* d_in, const int* in_sizes, int n_in,
                              void* d_out, int out_size, void* d_ws, size_t ws_size,
                              hipStream_t stream) {
  const float* x     = (const float*)d_in[0];
  const float* mask  = (const float*)d_in[1];
  const float* Wv    = (const float*)d_in[2];
  const float* bv    = (const float*)d_in[3];
  const float* Wk    = (const float*)d_in[4];
  const float* bk    = (const float*)d_in[5];
  const float* Wq    = (const float*)d_in[6];
  const float* bq    = (const float*)d_in[7];
  const float* Wout  = (const float*)d_in[8];
  const float* bout  = (const float*)d_in[9];
  const float* Wval  = (const float*)d_in[10];
  const float* bval  = (const float*)d_in[11];
  const float* Wadv1 = (const float*)d_in[12];
  const float* badv1 = (const float*)d_in[13];
  const float* Wadv2 = (const float*)d_in[14];
  const float* badv2 = (const float*)d_in[15];
  float* out = (float*)d_out;
  char* ws = (char*)d_ws;

  // workspace layout (bytes)
  unsigned short* q_bf   = (unsigned short*)(ws + 0);          // 16 MB
  unsigned short* Kf     = (unsigned short*)(ws + 16777216);   // 16 MB
  unsigned short* Vf     = (unsigned short*)(ws + 33554432);   // 16 MB
  unsigned short* out_at = (unsigned short*)(ws + 50331648);   // 16 MB
  float* value = (float*)(ws + 67108864);                      // 256 KB
  float* adv1  = (float*)(ws + 67371008);                      // 2 MB
  float* adv2  = (float*)(ws + 69468160);                      // 2 MB
  float* sums  = (float*)(ws + 71565312);                      // 2 KB
  unsigned short* Wf_hi = (unsigned short*)(ws + 71567360);    // 192 KB
  unsigned short* Wf_lo = (unsigned short*)(ws + 71763968);    // 192 KB
  unsigned short* WoutT = (unsigned short*)(ws + 71960576);    // 32 KB
  unsigned long long* bits = (unsigned long long*)(ws + 71993344);  // 16 MB

  prep_kernel<<<112, 256, 0, stream>>>(Wv, Wk, Wq, Wout, Wf_hi, Wf_lo, WoutT);
  fused_pp_kernel<<<3072, 256, 0, stream>>>(x, Wf_hi, Wf_lo, bq, bk, bv,
                                            q_bf, Kf, Vf, mask, bits);
  attn_kernel<<<512, 256, 0, stream>>>(q_bf, Kf, Vf, bits, out_at);
  wout_heads_kernel<<<1024, 256, 0, stream>>>(out_at, WoutT, bout, Wval, bval,
                                              Wadv1, badv1, Wadv2, badv2,
                                              value, adv1, adv2);
  sums_kernel<<<32, 256, 0, stream>>>(adv1, adv2, sums);
  combine_kernel<<<4096, 256, 0, stream>>>(value, adv1, adv2, sums, out);
}

// Round 11
// 335.505 us; speedup vs baseline: 1.1940x; 1.1940x over previous
//
#include <hip/hip_runtime.h>
#include <hip/hip_bf16.h>

// BranchingQNetwork fused forward for MI355X (gfx950).
// B=32, N=2048, OBS=256, HID=128, n1=n2=8.
// v11: v7 baseline (separate prepack/proj; fusion was -50us, reverted) +
// (a) permlane P-transpose in attn (R7 order 32->16, verified by 3-element
//     trace; 4 distinct SSA values -> no reg-coalescing hazard),
// (b) proj standalone at 64 rows/block, 2 blocks/CU (code proven in v10).

typedef __attribute__((ext_vector_type(4))) float f32x4;
typedef __attribute__((ext_vector_type(8))) short bf16x8;
typedef __attribute__((ext_vector_type(4))) unsigned int u32x4;

#define LOG2E 1.44269504088896340736f
#define NEGC 9.0e15f

static __device__ __forceinline__ unsigned short f2bf(float f) {
  unsigned int x = __builtin_bit_cast(unsigned int, f);
  unsigned int r = (x + 0x7fffu + ((x >> 16) & 1u)) >> 16;   // RNE
  return (unsigned short)r;
}
static __device__ __forceinline__ float bf2f(unsigned short u) {
  return __builtin_bit_cast(float, ((unsigned int)u) << 16);
}
static __device__ __forceinline__ unsigned int pack2bf(float lo, float hi) {
  return (unsigned int)f2bf(lo) | ((unsigned int)f2bf(hi) << 16);
}
static __device__ __forceinline__ f32x4 mfma16(bf16x8 a, bf16x8 b, f32x4 c) {
  return __builtin_amdgcn_mfma_f32_16x16x32_bf16(a, b, c, 0, 0, 0);
}

// ---------------------------------------------------------------------------
// Kernel P: mask prepack (standalone, v7-proven). mask fp32 -> bitmask u64;
// word bits[row*32+T] covers kv T*64..+63, bit layout (j*16+u) = kv(4u+j).
// ---------------------------------------------------------------------------
__global__ __launch_bounds__(256) void prepack_kernel(const float* __restrict__ mask,
                                                      unsigned long long* __restrict__ bits) {
  const int lane = threadIdx.x & 63;
  const int gwave = (blockIdx.x << 2) | (threadIdx.x >> 6);  // 8192 waves
  const int T = lane & 3;
  const int sh = T << 4;                                     // 16*T
  for (int r = 0; r < 8; ++r) {
    const long row = (long)gwave * 8 + r;
    const float* mp = mask + row * 2048;
    unsigned long long* op = bits + row * 32;
#pragma unroll
    for (int g = 0; g < 8; ++g) {
      f32x4 v = *(const f32x4*)(mp + g * 256 + lane * 4);
      unsigned long long b0 = __ballot(v[0] != 0.0f);
      unsigned long long b1 = __ballot(v[1] != 0.0f);
      unsigned long long b2 = __ballot(v[2] != 0.0f);
      unsigned long long b3 = __ballot(v[3] != 0.0f);
      unsigned long long f0 = (b0 >> sh) & 0xFFFFull;
      unsigned long long f1 = (b1 >> sh) & 0xFFFFull;
      unsigned long long f2 = (b2 >> sh) & 0xFFFFull;
      unsigned long long f3 = (b3 >> sh) & 0xFFFFull;
      unsigned long long val = f0 | (f1 << 16) | (f2 << 32) | (f3 << 48);
      if (lane < 4) op[g * 4 + T] = val;
    }
  }
}

// ---------------------------------------------------------------------------
// Kernel 0: weight prep into FRAG-LINEAR layouts.
// ---------------------------------------------------------------------------
__global__ __launch_bounds__(256) void prep_kernel(
    const float* __restrict__ Wv, const float* __restrict__ Wk,
    const float* __restrict__ Wq, const float* __restrict__ Wout,
    unsigned short* __restrict__ Wf_hi, unsigned short* __restrict__ Wf_lo,
    unsigned short* __restrict__ WoutT) {
  int gid = blockIdx.x * 256 + threadIdx.x;
  if (gid < 12288) {                 // (kc, t, lane)
    int kc = gid / 1536;
    int rem = gid - kc * 1536;
    int t = rem >> 6, lane = rem & 63;
    int hf = lane & 15, qf = lane >> 4;
    int sec = t >> 3;
    int j = (t & 7) * 16 + hf;
    const float* W = (sec == 0) ? Wq : (sec == 1) ? Wk : Wv;
#pragma unroll
    for (int e = 0; e < 8; ++e) {
      int k = kc * 32 + qf * 8 + e;
      float w = W[k * 128 + j];
      unsigned short hi = f2bf(w);
      Wf_hi[gid * 8 + e] = hi;
      Wf_lo[gid * 8 + e] = f2bf(w - bf2f(hi));
    }
  } else if (gid < 12288 + 16384) {
    int i2 = gid - 12288;
    int j = i2 >> 7, c = i2 & 127;
    WoutT[i2] = f2bf(Wout[c * 128 + j]);
  }
}

// ---------------------------------------------------------------------------
// Kernel 1: QKV projection, standalone (code path proven in v10's proj role).
// 1024 blocks x 256 threads (4 waves, 64 rows/block), 2 blocks/CU.
// W staged per-kc in LDS; 3-pass hi/lo x*W MFMA; outputs via vbuf:
//   q -> row-major; Kf/Vf -> frag-linear (one 64-row kv tile per block).
// ---------------------------------------------------------------------------
__global__ __launch_bounds__(256, 2) void proj_kernel(
    const float* __restrict__ x,
    const unsigned short* __restrict__ Wf_hi, const unsigned short* __restrict__ Wf_lo,
    const float* __restrict__ bq, const float* __restrict__ bk, const float* __restrict__ bv,
    unsigned short* __restrict__ q_bf, unsigned short* __restrict__ Kf,
    unsigned short* __restrict__ Vf) {
  __shared__ bf16x8 wst_hi[1536];              // 24 KB
  __shared__ bf16x8 wst_lo[1536];              // 24 KB
  __shared__ unsigned short vbuf[9216];        // 18 KB (max of [64][136], [128][72])

  const int tid = threadIdx.x;
  const int lane = tid & 63, wid = tid >> 6;
  const long rbase = (long)blockIdx.x * 64;
  const int qq = lane >> 4, hh = lane & 15;
  const long rowA = rbase + wid * 16 + hh;
  const f32x4 zero4 = {0.f, 0.f, 0.f, 0.f};
  f32x4 acc[24];
#pragma unroll
  for (int t = 0; t < 24; ++t) acc[t] = zero4;

  for (int kc = 0; kc < 8; ++kc) {
    __syncthreads();
#pragma unroll
    for (int i = 0; i < 6; ++i) {
      int idx = i * 256 + tid;
      wst_hi[idx] = *(const bf16x8*)(Wf_hi + ((long)kc * 1536 + idx) * 8);
      wst_lo[idx] = *(const bf16x8*)(Wf_lo + ((long)kc * 1536 + idx) * 8);
    }
    __syncthreads();

    const float* xp = x + rowA * 256 + kc * 32 + qq * 8;
    f32x4 x0 = *(const f32x4*)xp;
    f32x4 x1 = *(const f32x4*)(xp + 4);
    bf16x8 ah, al;
#pragma unroll
    for (int j = 0; j < 8; ++j) {
      float f = (j < 4) ? x0[j] : x1[j - 4];
      unsigned short h = f2bf(f);
      ah[j] = (short)h;
      al[j] = (short)f2bf(f - bf2f(h));
    }
#pragma unroll
    for (int t = 0; t < 24; ++t) {
      bf16x8 bh = wst_hi[t * 64 + lane];
      bf16x8 bl = wst_lo[t * 64 + lane];
      acc[t] = mfma16(ah, bh, acc[t]);
      acc[t] = mfma16(al, bh, acc[t]);
      acc[t] = mfma16(ah, bl, acc[t]);
    }
  }

  const int rowL = wid * 16 + qq * 4;            // 0..63
  const int b = (int)(rbase >> 11);
  const int tbase = (int)((rbase & 2047) >> 6);  // one kv-tile per block

  for (int sec = 0; sec < 3; ++sec) {
    __syncthreads();
#pragma unroll
    for (int tp = 0; tp < 8; ++tp) {
      const int t = sec * 8 + tp;
      const int j = tp * 16 + hh;
      const float bias = (sec == 0) ? bq[j] : (sec == 1) ? bk[j] : bv[j];
#pragma unroll
      for (int r = 0; r < 4; ++r) {
        unsigned short h = f2bf(fmaxf(acc[t][r] + bias, 0.f));
        if (sec == 2) vbuf[j * 72 + rowL + r] = h;        // V transposed [h][n]
        else          vbuf[(rowL + r) * 136 + j] = h;
      }
    }
    __syncthreads();
    if (sec == 0) {
      // q: row-major coalesced store (64 rows x 128 cols; 32 cols/thread)
      const int row = tid >> 2, ch = tid & 3;
      bf16x8 w1 = *(const bf16x8*)&vbuf[row * 136 + ch * 32];
      bf16x8 w2 = *(const bf16x8*)&vbuf[row * 136 + ch * 32 + 8];
      bf16x8 w3 = *(const bf16x8*)&vbuf[row * 136 + ch * 32 + 16];
      bf16x8 w4 = *(const bf16x8*)&vbuf[row * 136 + ch * 32 + 24];
      unsigned short* op = q_bf + (rbase + row) * 128 + ch * 32;
      *(bf16x8*)op = w1;
      *(bf16x8*)(op + 8) = w2;
      *(bf16x8*)(op + 16) = w3;
      *(bf16x8*)(op + 24) = w4;
    } else if (sec == 1) {
      // k -> Kf frag order (one tile: 16 segs x 64 lanes)
#pragma unroll
      for (int it = 0; it < 4; ++it) {
        int gid = it * 256 + tid;                  // (seg, lane)
        int seg = gid >> 6, ln = gid & 63;         // seg = m*4+kc
        int m = seg >> 2, kc = seg & 3;
        int hf = ln & 15, qf = ln >> 4;
        bf16x8 w = *(const bf16x8*)&vbuf[(m * 16 + hf) * 136 + kc * 32 + qf * 8];
        long off = (((long)(b * 32 + tbase) * 16 + seg) * 64 + ln) * 8;
        *(bf16x8*)(Kf + off) = w;
      }
    } else {
      // v -> Vf frag order (from transposed vbuf[h][n])
#pragma unroll
      for (int it = 0; it < 4; ++it) {
        int gid = it * 256 + tid;                  // (seg, lane)
        int seg = gid >> 6, ln = gid & 63;         // seg = ht*2+c
        int ht = seg >> 1, c = seg & 1;
        int hf = ln & 15, qf = ln >> 4;
        bf16x8 w = *(const bf16x8*)&vbuf[(ht * 16 + hf) * 72 + c * 32 + qf * 8];
        long off = (((long)(b * 32 + tbase) * 16 + seg) * 64 + ln) * 8;
        *(bf16x8*)(Vf + off) = w;
      }
    }
  }
}

// ---------------------------------------------------------------------------
// Kernel 2: flash attention = v7 + permlane P-transpose (32-swap then
// 16-swap; element-movement order verified by 3-element trace). shfl_xor
// softmax reductions retained (proven). 512 blocks x 256 threads, 2/CU.
// ---------------------------------------------------------------------------
__global__ __launch_bounds__(256, 2) void attn_kernel(
    const unsigned short* __restrict__ q_bf, const unsigned short* __restrict__ Kf,
    const unsigned short* __restrict__ Vf,
    const unsigned long long* __restrict__ bits, unsigned short* __restrict__ out_att) {
  __shared__ bf16x8 kls[2][1024];   // 2 x 16 KB
  __shared__ bf16x8 vls[2][1024];   // 2 x 16 KB

  const int tid = threadIdx.x;
  const int lane = tid & 63, wid = tid >> 6;
  const int qq = lane >> 4, hh = lane & 15;
  const int orig = blockIdx.x;
  const int b = ((orig & 7) << 2) | ((orig >> 3) & 3);   // XCD-clustered batches
  const int nb = orig >> 5;                              // 0..15
  const long qbase = (long)b * 2048 + nb * 128 + wid * 32;

  const f32x4 zero4 = {0.f, 0.f, 0.f, 0.f};

  bf16x8 qh[2][4];
#pragma unroll
  for (int ctq = 0; ctq < 2; ++ctq)
#pragma unroll
    for (int kc = 0; kc < 4; ++kc)
      qh[ctq][kc] = *(const bf16x8*)(q_bf + (qbase + ctq * 16 + hh) * 128 + kc * 32 + qq * 8);

  const unsigned long long* br0 = bits + (qbase + hh) * 32;
  const unsigned long long* br1 = bits + (qbase + 16 + hh) * 32;
  const unsigned short* kf0 = Kf + (long)(b * 32) * 8192;
  const unsigned short* vf0 = Vf + (long)(b * 32) * 8192;

  f32x4 o_acc[8][2];
#pragma unroll
  for (int ht = 0; ht < 8; ++ht) { o_acc[ht][0] = zero4; o_acc[ht][1] = zero4; }
  float m_run[2] = {-3.0e38f, -3.0e38f};
  float l_run[2] = {0.f, 0.f};

  // staging: wave wid owns segments wid*8 .. wid*8+7 (seg<16: K, else V)
  bf16x8 stg[8];
  const int seg0 = wid * 8;
  auto LOADREG = [&](int t) {
#pragma unroll
    for (int i = 0; i < 8; ++i) {
      int seg = seg0 + i;
      const unsigned short* src = (seg < 16)
          ? kf0 + (long)t * 8192 + (seg * 64 + lane) * 8
          : vf0 + (long)t * 8192 + ((seg - 16) * 64 + lane) * 8;
      stg[i] = *(const bf16x8*)src;
    }
  };
  auto WRITEBUF = [&](int nb2) {
#pragma unroll
    for (int i = 0; i < 8; ++i) {
      int seg = seg0 + i;
      if (seg < 16) kls[nb2][seg * 64 + lane] = stg[i];
      else          vls[nb2][(seg - 16) * 64 + lane] = stg[i];
    }
  };

  LOADREG(0);
  WRITEBUF(0);
  LOADREG(1);
  __syncthreads();

  unsigned long long bc0 = br0[0];
  unsigned long long bc1 = br1[0];
  int cur = 0;

  for (int t = 0; t < 32; ++t) {
    unsigned long long bn0 = 0, bn1 = 0;
    if (t + 1 < 32) { bn0 = br0[t + 1]; bn1 = br1[t + 1]; }

    // next-tile staging issued BEFORE compute
    if (t + 1 < 32) WRITEBUF(cur ^ 1);
    if (t + 2 < 32) LOADREG(t + 2);

    // S^T = K·Q^T from LDS (conflict-free lane*16 reads)
    f32x4 s[2][4];
#pragma unroll
    for (int m = 0; m < 4; ++m) { s[0][m] = zero4; s[1][m] = zero4; }
    __builtin_amdgcn_s_setprio(1);
#pragma unroll
    for (int m = 0; m < 4; ++m) {
      bf16x8 khf[4];
#pragma unroll
      for (int kc = 0; kc < 4; ++kc) khf[kc] = kls[cur][(m * 4 + kc) * 64 + lane];
#pragma unroll
      for (int kc = 0; kc < 4; ++kc)
#pragma unroll
        for (int ctq = 0; ctq < 2; ++ctq)
          s[ctq][m] = mfma16(khf[kc], qh[ctq][kc], s[ctq][m]);
    }
    __builtin_amdgcn_s_setprio(0);

    // bitmask select; bit layout: (bc >> qq) bit (r*16 + m*4)
    {
      const unsigned long long bb0 = bc0 >> qq;
      const unsigned long long bb1 = bc1 >> qq;
#pragma unroll
      for (int m = 0; m < 4; ++m)
#pragma unroll
        for (int r = 0; r < 4; ++r) {
          const int sh = r * 16 + m * 4;
          s[0][m][r] = ((bb0 >> sh) & 1ull) ? s[0][m][r] : -NEGC;
          s[1][m][r] = ((bb1 >> sh) & 1ull) ? s[1][m][r] : -NEGC;
        }
    }

    // fp32 online softmax, threshold defer-max (exact: P <= e^8)
    unsigned int pk[2][4][2];
#pragma unroll
    for (int ctq = 0; ctq < 2; ++ctq) {
      float mx = s[ctq][0][0];
#pragma unroll
      for (int m = 0; m < 4; ++m)
#pragma unroll
        for (int r = 0; r < 4; ++r) mx = fmaxf(mx, s[ctq][m][r]);
      mx = fmaxf(mx, __shfl_xor(mx, 16, 64));
      mx = fmaxf(mx, __shfl_xor(mx, 32, 64));
      if (__any(mx > m_run[ctq] + 8.0f)) {
        float mnew = fmaxf(m_run[ctq], mx);
        float sc = exp2f((m_run[ctq] - mnew) * LOG2E);
        m_run[ctq] = mnew;
        l_run[ctq] *= sc;
#pragma unroll
        for (int ht = 0; ht < 8; ++ht) o_acc[ht][ctq] *= sc;
      }
      float ps = 0.f;
#pragma unroll
      for (int m = 0; m < 4; ++m)
#pragma unroll
        for (int r = 0; r < 4; ++r) {
          float p = exp2f((s[ctq][m][r] - m_run[ctq]) * LOG2E);
          s[ctq][m][r] = p;
          ps += p;
        }
      ps += __shfl_xor(ps, 16, 64);
      ps += __shfl_xor(ps, 32, 64);
      l_run[ctq] += ps;
#pragma unroll
      for (int m = 0; m < 4; ++m) {
        pk[ctq][m][0] = pack2bf(s[ctq][m][0], s[ctq][m][1]);
        pk[ctq][m][1] = pack2bf(s[ctq][m][2], s[ctq][m][3]);
      }
    }

    // redistribute P (C layout) -> B-frag layout via permlane swaps.
    // Element movement (l1,l0,r1,r0): (q1,q0,w1,w0) <- element starting at
    // lane(q0,w1), reg(q1,w0): 3-cycle = swap(l1<->r1) [permlane32 FIRST]
    // then swap(l0<->r1) [permlane16]. Pairs: (a,cc) and (bb,d) both steps.
    // 4 distinct SSA values -> allocator keeps distinct VGPRs (no self-swap).
    bf16x8 pb[2][2];
#pragma unroll
    for (int ctq = 0; ctq < 2; ++ctq)
#pragma unroll
      for (int c = 0; c < 2; ++c) {
        unsigned int a  = pk[ctq][2 * c][0];
        unsigned int bb = pk[ctq][2 * c][1];
        unsigned int cc = pk[ctq][2 * c + 1][0];
        unsigned int d  = pk[ctq][2 * c + 1][1];
        asm("v_permlane32_swap_b32 %0, %1" : "+v"(a),  "+v"(cc));
        asm("v_permlane32_swap_b32 %0, %1" : "+v"(bb), "+v"(d));
        asm("v_permlane16_swap_b32 %0, %1" : "+v"(a),  "+v"(cc));
        asm("v_permlane16_swap_b32 %0, %1" : "+v"(bb), "+v"(d));
        u32x4 w;
        w[0] = a; w[1] = bb; w[2] = cc; w[3] = d;
        pb[ctq][c] = __builtin_bit_cast(bf16x8, w);
      }

    // O^T += V^T · P from LDS
    __builtin_amdgcn_s_setprio(1);
#pragma unroll
    for (int ht = 0; ht < 8; ++ht)
#pragma unroll
      for (int c = 0; c < 2; ++c) {
        bf16x8 vf = vls[cur][(ht * 2 + c) * 64 + lane];
#pragma unroll
        for (int ctq = 0; ctq < 2; ++ctq)
          o_acc[ht][ctq] = mfma16(vf, pb[ctq][c], o_acc[ht][ctq]);
      }
    __builtin_amdgcn_s_setprio(0);

    __syncthreads();   // single barrier per tile
    cur ^= 1;
    bc0 = bn0;
    bc1 = bn1;
  }

  // epilogue: normalize, store bf16. O^T frag: row h = ht*16+qq*4+r, col q=hh.
#pragma unroll
  for (int ctq = 0; ctq < 2; ++ctq) {
    float inv = 1.0f / l_run[ctq];
    const long row = qbase + ctq * 16 + hh;
#pragma unroll
    for (int ht = 0; ht < 8; ++ht) {
      f32x4 o = o_acc[ht][ctq];
      uint2 w;
      w.x = pack2bf(o[0] * inv, o[1] * inv);
      w.y = pack2bf(o[2] * inv, o[3] * inv);
      *(uint2*)(out_att + row * 128 + ht * 16 + qq * 4) = w;
    }
  }
}

// ---------------------------------------------------------------------------
// Kernel 3: out = relu(out_att @ Wout + bout) fused with the three heads.
// ---------------------------------------------------------------------------
__global__ __launch_bounds__(256) void wout_heads_kernel(
    const unsigned short* __restrict__ out_att, const unsigned short* __restrict__ WoutT,
    const float* __restrict__ bout,
    const float* __restrict__ Wval, const float* __restrict__ bval,
    const float* __restrict__ Wadv1, const float* __restrict__ badv1,
    const float* __restrict__ Wadv2, const float* __restrict__ badv2,
    float* __restrict__ value, float* __restrict__ adv1, float* __restrict__ adv2) {
  const int lane = threadIdx.x & 63, wid = threadIdx.x >> 6;
  const int qq = lane >> 4, hh = lane & 15;
  const long rowA = (long)blockIdx.x * 64 + wid * 16 + hh;
  const f32x4 zero4 = {0.f, 0.f, 0.f, 0.f};
  f32x4 acc[8];
#pragma unroll
  for (int t = 0; t < 8; ++t) acc[t] = zero4;
#pragma unroll
  for (int kc = 0; kc < 4; ++kc) {
    bf16x8 af = *(const bf16x8*)(out_att + rowA * 128 + kc * 32 + qq * 8);
#pragma unroll
    for (int t = 0; t < 8; ++t) {
      bf16x8 bf = *(const bf16x8*)(WoutT + (t * 16 + hh) * 128 + kc * 32 + qq * 8);
      acc[t] = mfma16(af, bf, acc[t]);
    }
  }
  float pv[4] = {0.f, 0.f, 0.f, 0.f};
  float pa1[4][8], pa2[4][8];
#pragma unroll
  for (int r = 0; r < 4; ++r)
#pragma unroll
    for (int j = 0; j < 8; ++j) { pa1[r][j] = 0.f; pa2[r][j] = 0.f; }
#pragma unroll
  for (int t = 0; t < 8; ++t) {
    const int col = t * 16 + hh;
    const float bo = bout[col];
    const float wv = Wval[col];
    const f32x4 w1a = *(const f32x4*)(Wadv1 + col * 8);
    const f32x4 w1b = *(const f32x4*)(Wadv1 + col * 8 + 4);
    const f32x4 w2a = *(const f32x4*)(Wadv2 + col * 8);
    const f32x4 w2b = *(const f32x4*)(Wadv2 + col * 8 + 4);
#pragma unroll
    for (int r = 0; r < 4; ++r) {
      float h = fmaxf(acc[t][r] + bo, 0.f);
      pv[r] += h * wv;
#pragma unroll
      for (int j = 0; j < 4; ++j) {
        pa1[r][j]     += h * w1a[j];
        pa1[r][4 + j] += h * w1b[j];
        pa2[r][j]     += h * w2a[j];
        pa2[r][4 + j] += h * w2b[j];
      }
    }
  }
#pragma unroll
  for (int r = 0; r < 4; ++r) {
#pragma unroll
    for (int s = 1; s < 16; s <<= 1) {
      pv[r] += __shfl_xor(pv[r], s, 64);
#pragma unroll
      for (int j = 0; j < 8; ++j) {
        pa1[r][j] += __shfl_xor(pa1[r][j], s, 64);
        pa2[r][j] += __shfl_xor(pa2[r][j], s, 64);
      }
    }
  }
  if (hh == 0) {
    const float bv0 = bval[0];
#pragma unroll
    for (int r = 0; r < 4; ++r) {
      const long row = (long)blockIdx.x * 64 + wid * 16 + qq * 4 + r;
      value[row] = pv[r] + bv0;
#pragma unroll
      for (int j = 0; j < 8; ++j) {
        adv1[row * 8 + j] = pa1[r][j] + badv1[j];
        adv2[row * 8 + j] = pa2[r][j] + badv2[j];
      }
    }
  }
}

// ---------------------------------------------------------------------------
// Kernel 4: per-batch column sums of adv1/adv2 over N (deterministic tree).
// ---------------------------------------------------------------------------
__global__ __launch_bounds__(256) void sums_kernel(const float* __restrict__ adv1,
                                                   const float* __restrict__ adv2,
                                                   float* __restrict__ sums) {
  const int b = blockIdx.x, tid = threadIdx.x;
  __shared__ float red[4][16];
  float p[16];
#pragma unroll
  for (int j = 0; j < 16; ++j) p[j] = 0.f;
  for (int n = tid; n < 2048; n += 256) {
    const long row = (long)b * 2048 + n;
    const f32x4 a1a = *(const f32x4*)(adv1 + row * 8);
    const f32x4 a1b = *(const f32x4*)(adv1 + row * 8 + 4);
    const f32x4 a2a = *(const f32x4*)(adv2 + row * 8);
    const f32x4 a2b = *(const f32x4*)(adv2 + row * 8 + 4);
#pragma unroll
    for (int j = 0; j < 4; ++j) {
      p[j] += a1a[j]; p[4 + j] += a1b[j];
      p[8 + j] += a2a[j]; p[12 + j] += a2b[j];
    }
  }
#pragma unroll
  for (int s = 1; s < 64; s <<= 1)
#pragma unroll
    for (int j = 0; j < 16; ++j) p[j] += __shfl_xor(p[j], s, 64);
  const int wid = tid >> 6;
  if ((tid & 63) == 0)
#pragma unroll
    for (int j = 0; j < 16; ++j) red[wid][j] = p[j];
  __syncthreads();
  if (tid < 16)
    sums[b * 16 + tid] = red[0][tid] + red[1][tid] + red[2][tid] + red[3][tid];
}

// ---------------------------------------------------------------------------
// Kernel 5: q1/q2 = value + adv - mean(adv). Output: [q1 | q2] fp32 flat.
// ---------------------------------------------------------------------------
__global__ void combine_kernel(const float* __restrict__ value, const float* __restrict__ adv1,
                               const float* __restrict__ adv2, const float* __restrict__ sums,
                               float* __restrict__ out) {
  const int idx = blockIdx.x * 256 + threadIdx.x;   // 0 .. 1048575
  const int half = 524288;
  const int which = (idx >= half) ? 1 : 0;
  const int rem = idx - which * half;
  const int b = rem >> 14;
  const int r2 = rem & 16383;
  const int n = r2 >> 3, j = r2 & 7;
  const long row = (long)b * 2048 + n;
  const float* adv = which ? adv2 : adv1;
  const float mean = sums[b * 16 + which * 8 + j] * (1.0f / 2048.0f);
  out[idx] = value[row] + adv[row * 8 + j] - mean;
}

// ---------------------------------------------------------------------------
extern "C" void kernel_launch(void* const* d_in, const int* in_sizes, int n_in,
                              void* d_out, int out_size, void* d_ws, size_t ws_size,
                              hipStream_t stream) {
  const float* x     = (const float*)d_in[0];
  const float* mask  = (const float*)d_in[1];
  const float* Wv    = (const float*)d_in[2];
  const float* bv    = (const float*)d_in[3];
  const float* Wk    = (const float*)d_in[4];
  const float* bk    = (const float*)d_in[5];
  const float* Wq    = (const float*)d_in[6];
  const float* bq    = (const float*)d_in[7];
  const float* Wout  = (const float*)d_in[8];
  const float* bout  = (const float*)d_in[9];
  const float* Wval  = (const float*)d_in[10];
  const float* bval  = (const float*)d_in[11];
  const float* Wadv1 = (const float*)d_in[12];
  const float* badv1 = (const float*)d_in[13];
  const float* Wadv2 = (const float*)d_in[14];
  const float* badv2 = (const float*)d_in[15];
  float* out = (float*)d_out;
  char* ws = (char*)d_ws;

  // workspace layout (bytes)
  unsigned short* q_bf   = (unsigned short*)(ws + 0);          // 16 MB
  unsigned short* Kf     = (unsigned short*)(ws + 16777216);   // 16 MB
  unsigned short* Vf     = (unsigned short*)(ws + 33554432);   // 16 MB
  unsigned short* out_at = (unsigned short*)(ws + 50331648);   // 16 MB
  float* value = (float*)(ws + 67108864);                      // 256 KB
  float* adv1  = (float*)(ws + 67371008);                      // 2 MB
  float* adv2  = (float*)(ws + 69468160);                      // 2 MB
  float* sums  = (float*)(ws + 71565312);                      // 2 KB
  unsigned short* Wf_hi = (unsigned short*)(ws + 71567360);    // 192 KB
  unsigned short* Wf_lo = (unsigned short*)(ws + 71763968);    // 192 KB
  unsigned short* WoutT = (unsigned short*)(ws + 71960576);    // 32 KB
  unsigned long long* bits = (unsigned long long*)(ws + 71993344);  // 16 MB

  prepack_kernel<<<2048, 256, 0, stream>>>(mask, bits);
  prep_kernel<<<112, 256, 0, stream>>>(Wv, Wk, Wq, Wout, Wf_hi, Wf_lo, WoutT);
  proj_kernel<<<1024, 256, 0, stream>>>(x, Wf_hi, Wf_lo, bq, bk, bv, q_bf, Kf, Vf);
  attn_kernel<<<512, 256, 0, stream>>>(q_bf, Kf, Vf, bits, out_at);
  wout_heads_kernel<<<1024, 256, 0, stream>>>(out_at, WoutT, bout, Wval, bval,
                                              Wadv1, badv1, Wadv2, badv2,
                                              value, adv1, adv2);
  sums_kernel<<<32, 256, 0, stream>>>(adv1, adv2, sums);
  combine_kernel<<<4096, 256, 0, stream>>>(value, adv1, adv2, sums, out);
}

// Round 12
// 331.029 us; speedup vs baseline: 1.2101x; 1.0135x over previous
//
#include <hip/hip_runtime.h>
#include <hip/hip_bf16.h>

// BranchingQNetwork fused forward for MI355X (gfx950).
// B=32, N=2048, OBS=256, HID=128, n1=n2=8.
// v12: v11 (proven) + launch consolidation:
//  - sums fused into combine (8 blocks/batch, redundant deterministic sums)
//  - prep folded into prepack (blocks >= 2048)
// attn/proj/wout byte-identical to v11.

typedef __attribute__((ext_vector_type(4))) float f32x4;
typedef __attribute__((ext_vector_type(8))) short bf16x8;
typedef __attribute__((ext_vector_type(4))) unsigned int u32x4;

#define LOG2E 1.44269504088896340736f
#define NEGC 9.0e15f

static __device__ __forceinline__ unsigned short f2bf(float f) {
  unsigned int x = __builtin_bit_cast(unsigned int, f);
  unsigned int r = (x + 0x7fffu + ((x >> 16) & 1u)) >> 16;   // RNE
  return (unsigned short)r;
}
static __device__ __forceinline__ float bf2f(unsigned short u) {
  return __builtin_bit_cast(float, ((unsigned int)u) << 16);
}
static __device__ __forceinline__ unsigned int pack2bf(float lo, float hi) {
  return (unsigned int)f2bf(lo) | ((unsigned int)f2bf(hi) << 16);
}
static __device__ __forceinline__ f32x4 mfma16(bf16x8 a, bf16x8 b, f32x4 c) {
  return __builtin_amdgcn_mfma_f32_16x16x32_bf16(a, b, c, 0, 0, 0);
}

// ---------------------------------------------------------------------------
// Kernel P: mask prepack (blocks 0..2047) + weight prep (blocks 2048..2159).
// prepack: mask fp32 -> bitmask u64; word bits[row*32+T] covers kv T*64..+63,
// bit layout (j*16+u) = kv(4u+j). prep: Wf frag-linear hi/lo + WoutT.
// ---------------------------------------------------------------------------
__global__ __launch_bounds__(256) void prepack_kernel(
    const float* __restrict__ mask, unsigned long long* __restrict__ bits,
    const float* __restrict__ Wv, const float* __restrict__ Wk,
    const float* __restrict__ Wq, const float* __restrict__ Wout,
    unsigned short* __restrict__ Wf_hi, unsigned short* __restrict__ Wf_lo,
    unsigned short* __restrict__ WoutT) {
  if (blockIdx.x >= 2048) {
    // ------- weight prep role (112 blocks) -------
    int gid = (blockIdx.x - 2048) * 256 + threadIdx.x;
    if (gid < 12288) {                 // (kc, t, lane)
      int kc = gid / 1536;
      int rem = gid - kc * 1536;
      int t = rem >> 6, lane = rem & 63;
      int hf = lane & 15, qf = lane >> 4;
      int sec = t >> 3;
      int j = (t & 7) * 16 + hf;
      const float* W = (sec == 0) ? Wq : (sec == 1) ? Wk : Wv;
#pragma unroll
      for (int e = 0; e < 8; ++e) {
        int k = kc * 32 + qf * 8 + e;
        float w = W[k * 128 + j];
        unsigned short hi = f2bf(w);
        Wf_hi[gid * 8 + e] = hi;
        Wf_lo[gid * 8 + e] = f2bf(w - bf2f(hi));
      }
    } else if (gid < 12288 + 16384) {
      int i2 = gid - 12288;
      int j = i2 >> 7, c = i2 & 127;
      WoutT[i2] = f2bf(Wout[c * 128 + j]);
    }
    return;
  }
  // ------- mask prepack role -------
  const int lane = threadIdx.x & 63;
  const int gwave = (blockIdx.x << 2) | (threadIdx.x >> 6);  // 8192 waves
  const int T = lane & 3;
  const int sh = T << 4;                                     // 16*T
  for (int r = 0; r < 8; ++r) {
    const long row = (long)gwave * 8 + r;
    const float* mp = mask + row * 2048;
    unsigned long long* op = bits + row * 32;
#pragma unroll
    for (int g = 0; g < 8; ++g) {
      f32x4 v = *(const f32x4*)(mp + g * 256 + lane * 4);
      unsigned long long b0 = __ballot(v[0] != 0.0f);
      unsigned long long b1 = __ballot(v[1] != 0.0f);
      unsigned long long b2 = __ballot(v[2] != 0.0f);
      unsigned long long b3 = __ballot(v[3] != 0.0f);
      unsigned long long f0 = (b0 >> sh) & 0xFFFFull;
      unsigned long long f1 = (b1 >> sh) & 0xFFFFull;
      unsigned long long f2 = (b2 >> sh) & 0xFFFFull;
      unsigned long long f3 = (b3 >> sh) & 0xFFFFull;
      unsigned long long val = f0 | (f1 << 16) | (f2 << 32) | (f3 << 48);
      if (lane < 4) op[g * 4 + T] = val;
    }
  }
}

// ---------------------------------------------------------------------------
// Kernel 1: QKV projection (v11-proven). 1024 blocks x 256 threads
// (4 waves, 64 rows/block), 2 blocks/CU. W staged per-kc in LDS; 3-pass
// hi/lo x*W MFMA; q -> row-major; Kf/Vf -> frag-linear.
// ---------------------------------------------------------------------------
__global__ __launch_bounds__(256, 2) void proj_kernel(
    const float* __restrict__ x,
    const unsigned short* __restrict__ Wf_hi, const unsigned short* __restrict__ Wf_lo,
    const float* __restrict__ bq, const float* __restrict__ bk, const float* __restrict__ bv,
    unsigned short* __restrict__ q_bf, unsigned short* __restrict__ Kf,
    unsigned short* __restrict__ Vf) {
  __shared__ bf16x8 wst_hi[1536];              // 24 KB
  __shared__ bf16x8 wst_lo[1536];              // 24 KB
  __shared__ unsigned short vbuf[9216];        // 18 KB

  const int tid = threadIdx.x;
  const int lane = tid & 63, wid = tid >> 6;
  const long rbase = (long)blockIdx.x * 64;
  const int qq = lane >> 4, hh = lane & 15;
  const long rowA = rbase + wid * 16 + hh;
  const f32x4 zero4 = {0.f, 0.f, 0.f, 0.f};
  f32x4 acc[24];
#pragma unroll
  for (int t = 0; t < 24; ++t) acc[t] = zero4;

  for (int kc = 0; kc < 8; ++kc) {
    __syncthreads();
#pragma unroll
    for (int i = 0; i < 6; ++i) {
      int idx = i * 256 + tid;
      wst_hi[idx] = *(const bf16x8*)(Wf_hi + ((long)kc * 1536 + idx) * 8);
      wst_lo[idx] = *(const bf16x8*)(Wf_lo + ((long)kc * 1536 + idx) * 8);
    }
    __syncthreads();

    const float* xp = x + rowA * 256 + kc * 32 + qq * 8;
    f32x4 x0 = *(const f32x4*)xp;
    f32x4 x1 = *(const f32x4*)(xp + 4);
    bf16x8 ah, al;
#pragma unroll
    for (int j = 0; j < 8; ++j) {
      float f = (j < 4) ? x0[j] : x1[j - 4];
      unsigned short h = f2bf(f);
      ah[j] = (short)h;
      al[j] = (short)f2bf(f - bf2f(h));
    }
#pragma unroll
    for (int t = 0; t < 24; ++t) {
      bf16x8 bh = wst_hi[t * 64 + lane];
      bf16x8 bl = wst_lo[t * 64 + lane];
      acc[t] = mfma16(ah, bh, acc[t]);
      acc[t] = mfma16(al, bh, acc[t]);
      acc[t] = mfma16(ah, bl, acc[t]);
    }
  }

  const int rowL = wid * 16 + qq * 4;            // 0..63
  const int b = (int)(rbase >> 11);
  const int tbase = (int)((rbase & 2047) >> 6);  // one kv-tile per block

  for (int sec = 0; sec < 3; ++sec) {
    __syncthreads();
#pragma unroll
    for (int tp = 0; tp < 8; ++tp) {
      const int t = sec * 8 + tp;
      const int j = tp * 16 + hh;
      const float bias = (sec == 0) ? bq[j] : (sec == 1) ? bk[j] : bv[j];
#pragma unroll
      for (int r = 0; r < 4; ++r) {
        unsigned short h = f2bf(fmaxf(acc[t][r] + bias, 0.f));
        if (sec == 2) vbuf[j * 72 + rowL + r] = h;        // V transposed [h][n]
        else          vbuf[(rowL + r) * 136 + j] = h;
      }
    }
    __syncthreads();
    if (sec == 0) {
      const int row = tid >> 2, ch = tid & 3;
      bf16x8 w1 = *(const bf16x8*)&vbuf[row * 136 + ch * 32];
      bf16x8 w2 = *(const bf16x8*)&vbuf[row * 136 + ch * 32 + 8];
      bf16x8 w3 = *(const bf16x8*)&vbuf[row * 136 + ch * 32 + 16];
      bf16x8 w4 = *(const bf16x8*)&vbuf[row * 136 + ch * 32 + 24];
      unsigned short* op = q_bf + (rbase + row) * 128 + ch * 32;
      *(bf16x8*)op = w1;
      *(bf16x8*)(op + 8) = w2;
      *(bf16x8*)(op + 16) = w3;
      *(bf16x8*)(op + 24) = w4;
    } else if (sec == 1) {
#pragma unroll
      for (int it = 0; it < 4; ++it) {
        int gid = it * 256 + tid;                  // (seg, lane)
        int seg = gid >> 6, ln = gid & 63;         // seg = m*4+kc
        int m = seg >> 2, kc = seg & 3;
        int hf = ln & 15, qf = ln >> 4;
        bf16x8 w = *(const bf16x8*)&vbuf[(m * 16 + hf) * 136 + kc * 32 + qf * 8];
        long off = (((long)(b * 32 + tbase) * 16 + seg) * 64 + ln) * 8;
        *(bf16x8*)(Kf + off) = w;
      }
    } else {
#pragma unroll
      for (int it = 0; it < 4; ++it) {
        int gid = it * 256 + tid;                  // (seg, lane)
        int seg = gid >> 6, ln = gid & 63;         // seg = ht*2+c
        int ht = seg >> 1, c = seg & 1;
        int hf = ln & 15, qf = ln >> 4;
        bf16x8 w = *(const bf16x8*)&vbuf[(ht * 16 + hf) * 72 + c * 32 + qf * 8];
        long off = (((long)(b * 32 + tbase) * 16 + seg) * 64 + ln) * 8;
        *(bf16x8*)(Vf + off) = w;
      }
    }
  }
}

// ---------------------------------------------------------------------------
// Kernel 2: flash attention (v11-proven: permlane P-transpose 32->16,
// shfl_xor reductions). 512 blocks x 256 threads, 2 blocks/CU.
// ---------------------------------------------------------------------------
__global__ __launch_bounds__(256, 2) void attn_kernel(
    const unsigned short* __restrict__ q_bf, const unsigned short* __restrict__ Kf,
    const unsigned short* __restrict__ Vf,
    const unsigned long long* __restrict__ bits, unsigned short* __restrict__ out_att) {
  __shared__ bf16x8 kls[2][1024];   // 2 x 16 KB
  __shared__ bf16x8 vls[2][1024];   // 2 x 16 KB

  const int tid = threadIdx.x;
  const int lane = tid & 63, wid = tid >> 6;
  const int qq = lane >> 4, hh = lane & 15;
  const int orig = blockIdx.x;
  const int b = ((orig & 7) << 2) | ((orig >> 3) & 3);   // XCD-clustered batches
  const int nb = orig >> 5;                              // 0..15
  const long qbase = (long)b * 2048 + nb * 128 + wid * 32;

  const f32x4 zero4 = {0.f, 0.f, 0.f, 0.f};

  bf16x8 qh[2][4];
#pragma unroll
  for (int ctq = 0; ctq < 2; ++ctq)
#pragma unroll
    for (int kc = 0; kc < 4; ++kc)
      qh[ctq][kc] = *(const bf16x8*)(q_bf + (qbase + ctq * 16 + hh) * 128 + kc * 32 + qq * 8);

  const unsigned long long* br0 = bits + (qbase + hh) * 32;
  const unsigned long long* br1 = bits + (qbase + 16 + hh) * 32;
  const unsigned short* kf0 = Kf + (long)(b * 32) * 8192;
  const unsigned short* vf0 = Vf + (long)(b * 32) * 8192;

  f32x4 o_acc[8][2];
#pragma unroll
  for (int ht = 0; ht < 8; ++ht) { o_acc[ht][0] = zero4; o_acc[ht][1] = zero4; }
  float m_run[2] = {-3.0e38f, -3.0e38f};
  float l_run[2] = {0.f, 0.f};

  // staging: wave wid owns segments wid*8 .. wid*8+7 (seg<16: K, else V)
  bf16x8 stg[8];
  const int seg0 = wid * 8;
  auto LOADREG = [&](int t) {
#pragma unroll
    for (int i = 0; i < 8; ++i) {
      int seg = seg0 + i;
      const unsigned short* src = (seg < 16)
          ? kf0 + (long)t * 8192 + (seg * 64 + lane) * 8
          : vf0 + (long)t * 8192 + ((seg - 16) * 64 + lane) * 8;
      stg[i] = *(const bf16x8*)src;
    }
  };
  auto WRITEBUF = [&](int nb2) {
#pragma unroll
    for (int i = 0; i < 8; ++i) {
      int seg = seg0 + i;
      if (seg < 16) kls[nb2][seg * 64 + lane] = stg[i];
      else          vls[nb2][(seg - 16) * 64 + lane] = stg[i];
    }
  };

  LOADREG(0);
  WRITEBUF(0);
  LOADREG(1);
  __syncthreads();

  unsigned long long bc0 = br0[0];
  unsigned long long bc1 = br1[0];
  int cur = 0;

  for (int t = 0; t < 32; ++t) {
    unsigned long long bn0 = 0, bn1 = 0;
    if (t + 1 < 32) { bn0 = br0[t + 1]; bn1 = br1[t + 1]; }

    // next-tile staging issued BEFORE compute
    if (t + 1 < 32) WRITEBUF(cur ^ 1);
    if (t + 2 < 32) LOADREG(t + 2);

    // S^T = K·Q^T from LDS (conflict-free lane*16 reads)
    f32x4 s[2][4];
#pragma unroll
    for (int m = 0; m < 4; ++m) { s[0][m] = zero4; s[1][m] = zero4; }
    __builtin_amdgcn_s_setprio(1);
#pragma unroll
    for (int m = 0; m < 4; ++m) {
      bf16x8 khf[4];
#pragma unroll
      for (int kc = 0; kc < 4; ++kc) khf[kc] = kls[cur][(m * 4 + kc) * 64 + lane];
#pragma unroll
      for (int kc = 0; kc < 4; ++kc)
#pragma unroll
        for (int ctq = 0; ctq < 2; ++ctq)
          s[ctq][m] = mfma16(khf[kc], qh[ctq][kc], s[ctq][m]);
    }
    __builtin_amdgcn_s_setprio(0);

    // bitmask select; bit layout: (bc >> qq) bit (r*16 + m*4)
    {
      const unsigned long long bb0 = bc0 >> qq;
      const unsigned long long bb1 = bc1 >> qq;
#pragma unroll
      for (int m = 0; m < 4; ++m)
#pragma unroll
        for (int r = 0; r < 4; ++r) {
          const int sh = r * 16 + m * 4;
          s[0][m][r] = ((bb0 >> sh) & 1ull) ? s[0][m][r] : -NEGC;
          s[1][m][r] = ((bb1 >> sh) & 1ull) ? s[1][m][r] : -NEGC;
        }
    }

    // fp32 online softmax, threshold defer-max (exact: P <= e^8)
    unsigned int pk[2][4][2];
#pragma unroll
    for (int ctq = 0; ctq < 2; ++ctq) {
      float mx = s[ctq][0][0];
#pragma unroll
      for (int m = 0; m < 4; ++m)
#pragma unroll
        for (int r = 0; r < 4; ++r) mx = fmaxf(mx, s[ctq][m][r]);
      mx = fmaxf(mx, __shfl_xor(mx, 16, 64));
      mx = fmaxf(mx, __shfl_xor(mx, 32, 64));
      if (__any(mx > m_run[ctq] + 8.0f)) {
        float mnew = fmaxf(m_run[ctq], mx);
        float sc = exp2f((m_run[ctq] - mnew) * LOG2E);
        m_run[ctq] = mnew;
        l_run[ctq] *= sc;
#pragma unroll
        for (int ht = 0; ht < 8; ++ht) o_acc[ht][ctq] *= sc;
      }
      float ps = 0.f;
#pragma unroll
      for (int m = 0; m < 4; ++m)
#pragma unroll
        for (int r = 0; r < 4; ++r) {
          float p = exp2f((s[ctq][m][r] - m_run[ctq]) * LOG2E);
          s[ctq][m][r] = p;
          ps += p;
        }
      ps += __shfl_xor(ps, 16, 64);
      ps += __shfl_xor(ps, 32, 64);
      l_run[ctq] += ps;
#pragma unroll
      for (int m = 0; m < 4; ++m) {
        pk[ctq][m][0] = pack2bf(s[ctq][m][0], s[ctq][m][1]);
        pk[ctq][m][1] = pack2bf(s[ctq][m][2], s[ctq][m][3]);
      }
    }

    // redistribute P (C layout) -> B-frag layout via permlane swaps
    // (32-swap then 16-swap; element-movement order verified, v11-proven).
    bf16x8 pb[2][2];
#pragma unroll
    for (int ctq = 0; ctq < 2; ++ctq)
#pragma unroll
      for (int c = 0; c < 2; ++c) {
        unsigned int a  = pk[ctq][2 * c][0];
        unsigned int bb = pk[ctq][2 * c][1];
        unsigned int cc = pk[ctq][2 * c + 1][0];
        unsigned int d  = pk[ctq][2 * c + 1][1];
        asm("v_permlane32_swap_b32 %0, %1" : "+v"(a),  "+v"(cc));
        asm("v_permlane32_swap_b32 %0, %1" : "+v"(bb), "+v"(d));
        asm("v_permlane16_swap_b32 %0, %1" : "+v"(a),  "+v"(cc));
        asm("v_permlane16_swap_b32 %0, %1" : "+v"(bb), "+v"(d));
        u32x4 w;
        w[0] = a; w[1] = bb; w[2] = cc; w[3] = d;
        pb[ctq][c] = __builtin_bit_cast(bf16x8, w);
      }

    // O^T += V^T · P from LDS
    __builtin_amdgcn_s_setprio(1);
#pragma unroll
    for (int ht = 0; ht < 8; ++ht)
#pragma unroll
      for (int c = 0; c < 2; ++c) {
        bf16x8 vf = vls[cur][(ht * 2 + c) * 64 + lane];
#pragma unroll
        for (int ctq = 0; ctq < 2; ++ctq)
          o_acc[ht][ctq] = mfma16(vf, pb[ctq][c], o_acc[ht][ctq]);
      }
    __builtin_amdgcn_s_setprio(0);

    __syncthreads();   // single barrier per tile
    cur ^= 1;
    bc0 = bn0;
    bc1 = bn1;
  }

  // epilogue: normalize, store bf16. O^T frag: row h = ht*16+qq*4+r, col q=hh.
#pragma unroll
  for (int ctq = 0; ctq < 2; ++ctq) {
    float inv = 1.0f / l_run[ctq];
    const long row = qbase + ctq * 16 + hh;
#pragma unroll
    for (int ht = 0; ht < 8; ++ht) {
      f32x4 o = o_acc[ht][ctq];
      uint2 w;
      w.x = pack2bf(o[0] * inv, o[1] * inv);
      w.y = pack2bf(o[2] * inv, o[3] * inv);
      *(uint2*)(out_att + row * 128 + ht * 16 + qq * 4) = w;
    }
  }
}

// ---------------------------------------------------------------------------
// Kernel 3: out = relu(out_att @ Wout + bout) fused with the three heads.
// ---------------------------------------------------------------------------
__global__ __launch_bounds__(256) void wout_heads_kernel(
    const unsigned short* __restrict__ out_att, const unsigned short* __restrict__ WoutT,
    const float* __restrict__ bout,
    const float* __restrict__ Wval, const float* __restrict__ bval,
    const float* __restrict__ Wadv1, const float* __restrict__ badv1,
    const float* __restrict__ Wadv2, const float* __restrict__ badv2,
    float* __restrict__ value, float* __restrict__ adv1, float* __restrict__ adv2) {
  const int lane = threadIdx.x & 63, wid = threadIdx.x >> 6;
  const int qq = lane >> 4, hh = lane & 15;
  const long rowA = (long)blockIdx.x * 64 + wid * 16 + hh;
  const f32x4 zero4 = {0.f, 0.f, 0.f, 0.f};
  f32x4 acc[8];
#pragma unroll
  for (int t = 0; t < 8; ++t) acc[t] = zero4;
#pragma unroll
  for (int kc = 0; kc < 4; ++kc) {
    bf16x8 af = *(const bf16x8*)(out_att + rowA * 128 + kc * 32 + qq * 8);
#pragma unroll
    for (int t = 0; t < 8; ++t) {
      bf16x8 bf = *(const bf16x8*)(WoutT + (t * 16 + hh) * 128 + kc * 32 + qq * 8);
      acc[t] = mfma16(af, bf, acc[t]);
    }
  }
  float pv[4] = {0.f, 0.f, 0.f, 0.f};
  float pa1[4][8], pa2[4][8];
#pragma unroll
  for (int r = 0; r < 4; ++r)
#pragma unroll
    for (int j = 0; j < 8; ++j) { pa1[r][j] = 0.f; pa2[r][j] = 0.f; }
#pragma unroll
  for (int t = 0; t < 8; ++t) {
    const int col = t * 16 + hh;
    const float bo = bout[col];
    const float wv = Wval[col];
    const f32x4 w1a = *(const f32x4*)(Wadv1 + col * 8);
    const f32x4 w1b = *(const f32x4*)(Wadv1 + col * 8 + 4);
    const f32x4 w2a = *(const f32x4*)(Wadv2 + col * 8);
    const f32x4 w2b = *(const f32x4*)(Wadv2 + col * 8 + 4);
#pragma unroll
    for (int r = 0; r < 4; ++r) {
      float h = fmaxf(acc[t][r] + bo, 0.f);
      pv[r] += h * wv;
#pragma unroll
      for (int j = 0; j < 4; ++j) {
        pa1[r][j]     += h * w1a[j];
        pa1[r][4 + j] += h * w1b[j];
        pa2[r][j]     += h * w2a[j];
        pa2[r][4 + j] += h * w2b[j];
      }
    }
  }
#pragma unroll
  for (int r = 0; r < 4; ++r) {
#pragma unroll
    for (int s = 1; s < 16; s <<= 1) {
      pv[r] += __shfl_xor(pv[r], s, 64);
#pragma unroll
      for (int j = 0; j < 8; ++j) {
        pa1[r][j] += __shfl_xor(pa1[r][j], s, 64);
        pa2[r][j] += __shfl_xor(pa2[r][j], s, 64);
      }
    }
  }
  if (hh == 0) {
    const float bv0 = bval[0];
#pragma unroll
    for (int r = 0; r < 4; ++r) {
      const long row = (long)blockIdx.x * 64 + wid * 16 + qq * 4 + r;
      value[row] = pv[r] + bv0;
#pragma unroll
      for (int j = 0; j < 8; ++j) {
        adv1[row * 8 + j] = pa1[r][j] + badv1[j];
        adv2[row * 8 + j] = pa2[r][j] + badv2[j];
      }
    }
  }
}

// ---------------------------------------------------------------------------
// Kernel 4: FUSED sums + combine. 256 blocks (8 per batch); each block
// redundantly computes its batch's column sums with the SAME deterministic
// tree (bit-identical across the 8 blocks), then writes its 1/8 slice of
// q1/q2. Removes the separate sums kernel + one adv round-trip.
// ---------------------------------------------------------------------------
__global__ __launch_bounds__(256) void combine_kernel(
    const float* __restrict__ value, const float* __restrict__ adv1,
    const float* __restrict__ adv2, float* __restrict__ out) {
  const int b = blockIdx.x >> 3;
  const int slice = blockIdx.x & 7;
  const int tid = threadIdx.x;
  __shared__ float red[4][16];

  float p[16];
#pragma unroll
  for (int j = 0; j < 16; ++j) p[j] = 0.f;
  for (int n = tid; n < 2048; n += 256) {
    const long row = (long)b * 2048 + n;
    const f32x4 a1a = *(const f32x4*)(adv1 + row * 8);
    const f32x4 a1b = *(const f32x4*)(adv1 + row * 8 + 4);
    const f32x4 a2a = *(const f32x4*)(adv2 + row * 8);
    const f32x4 a2b = *(const f32x4*)(adv2 + row * 8 + 4);
#pragma unroll
    for (int j = 0; j < 4; ++j) {
      p[j] += a1a[j]; p[4 + j] += a1b[j];
      p[8 + j] += a2a[j]; p[12 + j] += a2b[j];
    }
  }
#pragma unroll
  for (int s = 1; s < 64; s <<= 1)
#pragma unroll
    for (int j = 0; j < 16; ++j) p[j] += __shfl_xor(p[j], s, 64);
  const int wid = tid >> 6;
  if ((tid & 63) == 0)
#pragma unroll
    for (int j = 0; j < 16; ++j) red[wid][j] = p[j];
  __syncthreads();

  float mean1[8], mean2[8];
#pragma unroll
  for (int j = 0; j < 8; ++j) {
    mean1[j] = (red[0][j] + red[1][j] + red[2][j] + red[3][j]) * (1.0f / 2048.0f);
    mean2[j] = (red[0][8 + j] + red[1][8 + j] + red[2][8 + j] + red[3][8 + j]) * (1.0f / 2048.0f);
  }

  const int n = slice * 256 + tid;
  const long row = (long)b * 2048 + n;
  const float v = value[row];
  const f32x4 a1a = *(const f32x4*)(adv1 + row * 8);
  const f32x4 a1b = *(const f32x4*)(adv1 + row * 8 + 4);
  const f32x4 a2a = *(const f32x4*)(adv2 + row * 8);
  const f32x4 a2b = *(const f32x4*)(adv2 + row * 8 + 4);
  f32x4 o1a, o1b, o2a, o2b;
#pragma unroll
  for (int j = 0; j < 4; ++j) {
    o1a[j] = v + a1a[j] - mean1[j];
    o1b[j] = v + a1b[j] - mean1[4 + j];
    o2a[j] = v + a2a[j] - mean2[j];
    o2b[j] = v + a2b[j] - mean2[4 + j];
  }
  *(f32x4*)(out + row * 8) = o1a;
  *(f32x4*)(out + row * 8 + 4) = o1b;
  *(f32x4*)(out + 524288 + row * 8) = o2a;
  *(f32x4*)(out + 524288 + row * 8 + 4) = o2b;
}

// ---------------------------------------------------------------------------
extern "C" void kernel_launch(void* const* d_in, const int* in_sizes, int n_in,
                              void* d_out, int out_size, void* d_ws, size_t ws_size,
                              hipStream_t stream) {
  const float* x     = (const float*)d_in[0];
  const float* mask  = (const float*)d_in[1];
  const float* Wv    = (const float*)d_in[2];
  const float* bv    = (const float*)d_in[3];
  const float* Wk    = (const float*)d_in[4];
  const float* bk    = (const float*)d_in[5];
  const float* Wq    = (const float*)d_in[6];
  const float* bq    = (const float*)d_in[7];
  const float* Wout  = (const float*)d_in[8];
  const float* bout  = (const float*)d_in[9];
  const float* Wval  = (const float*)d_in[10];
  const float* bval  = (const float*)d_in[11];
  const float* Wadv1 = (const float*)d_in[12];
  const float* badv1 = (const float*)d_in[13];
  const float* Wadv2 = (const float*)d_in[14];
  const float* badv2 = (const float*)d_in[15];
  float* out = (float*)d_out;
  char* ws = (char*)d_ws;

  // workspace layout (bytes)
  unsigned short* q_bf   = (unsigned short*)(ws + 0);          // 16 MB
  unsigned short* Kf     = (unsigned short*)(ws + 16777216);   // 16 MB
  unsigned short* Vf     = (unsigned short*)(ws + 33554432);   // 16 MB
  unsigned short* out_at = (unsigned short*)(ws + 50331648);   // 16 MB
  float* value = (float*)(ws + 67108864);                      // 256 KB
  float* adv1  = (float*)(ws + 67371008);                      // 2 MB
  float* adv2  = (float*)(ws + 69468160);                      // 2 MB
  unsigned short* Wf_hi = (unsigned short*)(ws + 71567360);    // 192 KB
  unsigned short* Wf_lo = (unsigned short*)(ws + 71763968);    // 192 KB
  unsigned short* WoutT = (unsigned short*)(ws + 71960576);    // 32 KB
  unsigned long long* bits = (unsigned long long*)(ws + 71993344);  // 16 MB

  prepack_kernel<<<2160, 256, 0, stream>>>(mask, bits, Wv, Wk, Wq, Wout,
                                           Wf_hi, Wf_lo, WoutT);
  proj_kernel<<<1024, 256, 0, stream>>>(x, Wf_hi, Wf_lo, bq, bk, bv, q_bf, Kf, Vf);
  attn_kernel<<<512, 256, 0, stream>>>(q_bf, Kf, Vf, bits, out_at);
  wout_heads_kernel<<<1024, 256, 0, stream>>>(out_at, WoutT, bout, Wval, bval,
                                              Wadv1, badv1, Wadv2, badv2,
                                              value, adv1, adv2);
  combine_kernel<<<256, 256, 0, stream>>>(value, adv1, adv2, out);
}

// Round 13
// 324.001 us; speedup vs baseline: 1.2364x; 1.0217x over previous
//
#include <hip/hip_runtime.h>
#include <hip/hip_bf16.h>

// BranchingQNetwork fused forward for MI355X (gfx950).
// B=32, N=2048, OBS=256, HID=128, n1=n2=8.
// v13: v12 + v_cvt_pk_bf16_f32 (inline asm, RNE) replacing hand-rolled
// pack2bf in attn's P-pack and epilogue (~112 -> ~16 VALU instr/tile/wave;
// softmax VALU was the measured attn bottleneck).

typedef __attribute__((ext_vector_type(4))) float f32x4;
typedef __attribute__((ext_vector_type(8))) short bf16x8;
typedef __attribute__((ext_vector_type(4))) unsigned int u32x4;

#define LOG2E 1.44269504088896340736f
#define NEGC 9.0e15f

static __device__ __forceinline__ unsigned short f2bf(float f) {
  unsigned int x = __builtin_bit_cast(unsigned int, f);
  unsigned int r = (x + 0x7fffu + ((x >> 16) & 1u)) >> 16;   // RNE
  return (unsigned short)r;
}
static __device__ __forceinline__ float bf2f(unsigned short u) {
  return __builtin_bit_cast(float, ((unsigned int)u) << 16);
}
// HW packed f32x2 -> bf16x2 (RNE; dst.lo = bf16(lo), dst.hi = bf16(hi)).
static __device__ __forceinline__ unsigned int cvt_pk_bf16(float lo, float hi) {
  unsigned int r;
  asm("v_cvt_pk_bf16_f32 %0, %1, %2" : "=v"(r) : "v"(lo), "v"(hi));
  return r;
}
static __device__ __forceinline__ f32x4 mfma16(bf16x8 a, bf16x8 b, f32x4 c) {
  return __builtin_amdgcn_mfma_f32_16x16x32_bf16(a, b, c, 0, 0, 0);
}

// ---------------------------------------------------------------------------
// Kernel P: mask prepack (blocks 0..2047) + weight prep (blocks 2048..2159).
// prepack: mask fp32 -> bitmask u64; word bits[row*32+T] covers kv T*64..+63,
// bit layout (j*16+u) = kv(4u+j). prep: Wf frag-linear hi/lo + WoutT.
// ---------------------------------------------------------------------------
__global__ __launch_bounds__(256) void prepack_kernel(
    const float* __restrict__ mask, unsigned long long* __restrict__ bits,
    const float* __restrict__ Wv, const float* __restrict__ Wk,
    const float* __restrict__ Wq, const float* __restrict__ Wout,
    unsigned short* __restrict__ Wf_hi, unsigned short* __restrict__ Wf_lo,
    unsigned short* __restrict__ WoutT) {
  if (blockIdx.x >= 2048) {
    // ------- weight prep role (112 blocks) -------
    int gid = (blockIdx.x - 2048) * 256 + threadIdx.x;
    if (gid < 12288) {                 // (kc, t, lane)
      int kc = gid / 1536;
      int rem = gid - kc * 1536;
      int t = rem >> 6, lane = rem & 63;
      int hf = lane & 15, qf = lane >> 4;
      int sec = t >> 3;
      int j = (t & 7) * 16 + hf;
      const float* W = (sec == 0) ? Wq : (sec == 1) ? Wk : Wv;
#pragma unroll
      for (int e = 0; e < 8; ++e) {
        int k = kc * 32 + qf * 8 + e;
        float w = W[k * 128 + j];
        unsigned short hi = f2bf(w);
        Wf_hi[gid * 8 + e] = hi;
        Wf_lo[gid * 8 + e] = f2bf(w - bf2f(hi));
      }
    } else if (gid < 12288 + 16384) {
      int i2 = gid - 12288;
      int j = i2 >> 7, c = i2 & 127;
      WoutT[i2] = f2bf(Wout[c * 128 + j]);
    }
    return;
  }
  // ------- mask prepack role -------
  const int lane = threadIdx.x & 63;
  const int gwave = (blockIdx.x << 2) | (threadIdx.x >> 6);  // 8192 waves
  const int T = lane & 3;
  const int sh = T << 4;                                     // 16*T
  for (int r = 0; r < 8; ++r) {
    const long row = (long)gwave * 8 + r;
    const float* mp = mask + row * 2048;
    unsigned long long* op = bits + row * 32;
#pragma unroll
    for (int g = 0; g < 8; ++g) {
      f32x4 v = *(const f32x4*)(mp + g * 256 + lane * 4);
      unsigned long long b0 = __ballot(v[0] != 0.0f);
      unsigned long long b1 = __ballot(v[1] != 0.0f);
      unsigned long long b2 = __ballot(v[2] != 0.0f);
      unsigned long long b3 = __ballot(v[3] != 0.0f);
      unsigned long long f0 = (b0 >> sh) & 0xFFFFull;
      unsigned long long f1 = (b1 >> sh) & 0xFFFFull;
      unsigned long long f2 = (b2 >> sh) & 0xFFFFull;
      unsigned long long f3 = (b3 >> sh) & 0xFFFFull;
      unsigned long long val = f0 | (f1 << 16) | (f2 << 32) | (f3 << 48);
      if (lane < 4) op[g * 4 + T] = val;
    }
  }
}

// ---------------------------------------------------------------------------
// Kernel 1: QKV projection (v11-proven). 1024 blocks x 256 threads
// (4 waves, 64 rows/block), 2 blocks/CU. W staged per-kc in LDS; 3-pass
// hi/lo x*W MFMA; q -> row-major; Kf/Vf -> frag-linear.
// ---------------------------------------------------------------------------
__global__ __launch_bounds__(256, 2) void proj_kernel(
    const float* __restrict__ x,
    const unsigned short* __restrict__ Wf_hi, const unsigned short* __restrict__ Wf_lo,
    const float* __restrict__ bq, const float* __restrict__ bk, const float* __restrict__ bv,
    unsigned short* __restrict__ q_bf, unsigned short* __restrict__ Kf,
    unsigned short* __restrict__ Vf) {
  __shared__ bf16x8 wst_hi[1536];              // 24 KB
  __shared__ bf16x8 wst_lo[1536];              // 24 KB
  __shared__ unsigned short vbuf[9216];        // 18 KB

  const int tid = threadIdx.x;
  const int lane = tid & 63, wid = tid >> 6;
  const long rbase = (long)blockIdx.x * 64;
  const int qq = lane >> 4, hh = lane & 15;
  const long rowA = rbase + wid * 16 + hh;
  const f32x4 zero4 = {0.f, 0.f, 0.f, 0.f};
  f32x4 acc[24];
#pragma unroll
  for (int t = 0; t < 24; ++t) acc[t] = zero4;

  for (int kc = 0; kc < 8; ++kc) {
    __syncthreads();
#pragma unroll
    for (int i = 0; i < 6; ++i) {
      int idx = i * 256 + tid;
      wst_hi[idx] = *(const bf16x8*)(Wf_hi + ((long)kc * 1536 + idx) * 8);
      wst_lo[idx] = *(const bf16x8*)(Wf_lo + ((long)kc * 1536 + idx) * 8);
    }
    __syncthreads();

    const float* xp = x + rowA * 256 + kc * 32 + qq * 8;
    f32x4 x0 = *(const f32x4*)xp;
    f32x4 x1 = *(const f32x4*)(xp + 4);
    bf16x8 ah, al;
#pragma unroll
    for (int j = 0; j < 8; ++j) {
      float f = (j < 4) ? x0[j] : x1[j - 4];
      unsigned short h = f2bf(f);
      ah[j] = (short)h;
      al[j] = (short)f2bf(f - bf2f(h));
    }
#pragma unroll
    for (int t = 0; t < 24; ++t) {
      bf16x8 bh = wst_hi[t * 64 + lane];
      bf16x8 bl = wst_lo[t * 64 + lane];
      acc[t] = mfma16(ah, bh, acc[t]);
      acc[t] = mfma16(al, bh, acc[t]);
      acc[t] = mfma16(ah, bl, acc[t]);
    }
  }

  const int rowL = wid * 16 + qq * 4;            // 0..63
  const int b = (int)(rbase >> 11);
  const int tbase = (int)((rbase & 2047) >> 6);  // one kv-tile per block

  for (int sec = 0; sec < 3; ++sec) {
    __syncthreads();
#pragma unroll
    for (int tp = 0; tp < 8; ++tp) {
      const int t = sec * 8 + tp;
      const int j = tp * 16 + hh;
      const float bias = (sec == 0) ? bq[j] : (sec == 1) ? bk[j] : bv[j];
#pragma unroll
      for (int r = 0; r < 4; ++r) {
        unsigned short h = f2bf(fmaxf(acc[t][r] + bias, 0.f));
        if (sec == 2) vbuf[j * 72 + rowL + r] = h;        // V transposed [h][n]
        else          vbuf[(rowL + r) * 136 + j] = h;
      }
    }
    __syncthreads();
    if (sec == 0) {
      const int row = tid >> 2, ch = tid & 3;
      bf16x8 w1 = *(const bf16x8*)&vbuf[row * 136 + ch * 32];
      bf16x8 w2 = *(const bf16x8*)&vbuf[row * 136 + ch * 32 + 8];
      bf16x8 w3 = *(const bf16x8*)&vbuf[row * 136 + ch * 32 + 16];
      bf16x8 w4 = *(const bf16x8*)&vbuf[row * 136 + ch * 32 + 24];
      unsigned short* op = q_bf + (rbase + row) * 128 + ch * 32;
      *(bf16x8*)op = w1;
      *(bf16x8*)(op + 8) = w2;
      *(bf16x8*)(op + 16) = w3;
      *(bf16x8*)(op + 24) = w4;
    } else if (sec == 1) {
#pragma unroll
      for (int it = 0; it < 4; ++it) {
        int gid = it * 256 + tid;                  // (seg, lane)
        int seg = gid >> 6, ln = gid & 63;         // seg = m*4+kc
        int m = seg >> 2, kc = seg & 3;
        int hf = ln & 15, qf = ln >> 4;
        bf16x8 w = *(const bf16x8*)&vbuf[(m * 16 + hf) * 136 + kc * 32 + qf * 8];
        long off = (((long)(b * 32 + tbase) * 16 + seg) * 64 + ln) * 8;
        *(bf16x8*)(Kf + off) = w;
      }
    } else {
#pragma unroll
      for (int it = 0; it < 4; ++it) {
        int gid = it * 256 + tid;                  // (seg, lane)
        int seg = gid >> 6, ln = gid & 63;         // seg = ht*2+c
        int ht = seg >> 1, c = seg & 1;
        int hf = ln & 15, qf = ln >> 4;
        bf16x8 w = *(const bf16x8*)&vbuf[(ht * 16 + hf) * 72 + c * 32 + qf * 8];
        long off = (((long)(b * 32 + tbase) * 16 + seg) * 64 + ln) * 8;
        *(bf16x8*)(Vf + off) = w;
      }
    }
  }
}

// ---------------------------------------------------------------------------
// Kernel 2: flash attention (v11-proven structure: permlane P-transpose
// 32->16, shfl_xor reductions) + cvt_pk_bf16 packing (new in v13).
// 512 blocks x 256 threads, 2 blocks/CU.
// ---------------------------------------------------------------------------
__global__ __launch_bounds__(256, 2) void attn_kernel(
    const unsigned short* __restrict__ q_bf, const unsigned short* __restrict__ Kf,
    const unsigned short* __restrict__ Vf,
    const unsigned long long* __restrict__ bits, unsigned short* __restrict__ out_att) {
  __shared__ bf16x8 kls[2][1024];   // 2 x 16 KB
  __shared__ bf16x8 vls[2][1024];   // 2 x 16 KB

  const int tid = threadIdx.x;
  const int lane = tid & 63, wid = tid >> 6;
  const int qq = lane >> 4, hh = lane & 15;
  const int orig = blockIdx.x;
  const int b = ((orig & 7) << 2) | ((orig >> 3) & 3);   // XCD-clustered batches
  const int nb = orig >> 5;                              // 0..15
  const long qbase = (long)b * 2048 + nb * 128 + wid * 32;

  const f32x4 zero4 = {0.f, 0.f, 0.f, 0.f};

  bf16x8 qh[2][4];
#pragma unroll
  for (int ctq = 0; ctq < 2; ++ctq)
#pragma unroll
    for (int kc = 0; kc < 4; ++kc)
      qh[ctq][kc] = *(const bf16x8*)(q_bf + (qbase + ctq * 16 + hh) * 128 + kc * 32 + qq * 8);

  const unsigned long long* br0 = bits + (qbase + hh) * 32;
  const unsigned long long* br1 = bits + (qbase + 16 + hh) * 32;
  const unsigned short* kf0 = Kf + (long)(b * 32) * 8192;
  const unsigned short* vf0 = Vf + (long)(b * 32) * 8192;

  f32x4 o_acc[8][2];
#pragma unroll
  for (int ht = 0; ht < 8; ++ht) { o_acc[ht][0] = zero4; o_acc[ht][1] = zero4; }
  float m_run[2] = {-3.0e38f, -3.0e38f};
  float l_run[2] = {0.f, 0.f};

  // staging: wave wid owns segments wid*8 .. wid*8+7 (seg<16: K, else V)
  bf16x8 stg[8];
  const int seg0 = wid * 8;
  auto LOADREG = [&](int t) {
#pragma unroll
    for (int i = 0; i < 8; ++i) {
      int seg = seg0 + i;
      const unsigned short* src = (seg < 16)
          ? kf0 + (long)t * 8192 + (seg * 64 + lane) * 8
          : vf0 + (long)t * 8192 + ((seg - 16) * 64 + lane) * 8;
      stg[i] = *(const bf16x8*)src;
    }
  };
  auto WRITEBUF = [&](int nb2) {
#pragma unroll
    for (int i = 0; i < 8; ++i) {
      int seg = seg0 + i;
      if (seg < 16) kls[nb2][seg * 64 + lane] = stg[i];
      else          vls[nb2][(seg - 16) * 64 + lane] = stg[i];
    }
  };

  LOADREG(0);
  WRITEBUF(0);
  LOADREG(1);
  __syncthreads();

  unsigned long long bc0 = br0[0];
  unsigned long long bc1 = br1[0];
  int cur = 0;

  for (int t = 0; t < 32; ++t) {
    unsigned long long bn0 = 0, bn1 = 0;
    if (t + 1 < 32) { bn0 = br0[t + 1]; bn1 = br1[t + 1]; }

    // next-tile staging issued BEFORE compute
    if (t + 1 < 32) WRITEBUF(cur ^ 1);
    if (t + 2 < 32) LOADREG(t + 2);

    // S^T = K·Q^T from LDS (conflict-free lane*16 reads)
    f32x4 s[2][4];
#pragma unroll
    for (int m = 0; m < 4; ++m) { s[0][m] = zero4; s[1][m] = zero4; }
    __builtin_amdgcn_s_setprio(1);
#pragma unroll
    for (int m = 0; m < 4; ++m) {
      bf16x8 khf[4];
#pragma unroll
      for (int kc = 0; kc < 4; ++kc) khf[kc] = kls[cur][(m * 4 + kc) * 64 + lane];
#pragma unroll
      for (int kc = 0; kc < 4; ++kc)
#pragma unroll
        for (int ctq = 0; ctq < 2; ++ctq)
          s[ctq][m] = mfma16(khf[kc], qh[ctq][kc], s[ctq][m]);
    }
    __builtin_amdgcn_s_setprio(0);

    // bitmask select; bit layout: (bc >> qq) bit (r*16 + m*4)
    {
      const unsigned long long bb0 = bc0 >> qq;
      const unsigned long long bb1 = bc1 >> qq;
#pragma unroll
      for (int m = 0; m < 4; ++m)
#pragma unroll
        for (int r = 0; r < 4; ++r) {
          const int sh = r * 16 + m * 4;
          s[0][m][r] = ((bb0 >> sh) & 1ull) ? s[0][m][r] : -NEGC;
          s[1][m][r] = ((bb1 >> sh) & 1ull) ? s[1][m][r] : -NEGC;
        }
    }

    // fp32 online softmax, threshold defer-max (exact: P <= e^8)
    unsigned int pk[2][4][2];
#pragma unroll
    for (int ctq = 0; ctq < 2; ++ctq) {
      float mx = s[ctq][0][0];
#pragma unroll
      for (int m = 0; m < 4; ++m)
#pragma unroll
        for (int r = 0; r < 4; ++r) mx = fmaxf(mx, s[ctq][m][r]);
      mx = fmaxf(mx, __shfl_xor(mx, 16, 64));
      mx = fmaxf(mx, __shfl_xor(mx, 32, 64));
      if (__any(mx > m_run[ctq] + 8.0f)) {
        float mnew = fmaxf(m_run[ctq], mx);
        float sc = exp2f((m_run[ctq] - mnew) * LOG2E);
        m_run[ctq] = mnew;
        l_run[ctq] *= sc;
#pragma unroll
        for (int ht = 0; ht < 8; ++ht) o_acc[ht][ctq] *= sc;
      }
      float ps = 0.f;
#pragma unroll
      for (int m = 0; m < 4; ++m)
#pragma unroll
        for (int r = 0; r < 4; ++r) {
          float p = exp2f((s[ctq][m][r] - m_run[ctq]) * LOG2E);
          s[ctq][m][r] = p;
          ps += p;
        }
      ps += __shfl_xor(ps, 16, 64);
      ps += __shfl_xor(ps, 32, 64);
      l_run[ctq] += ps;
      // P -> bf16 pairs via HW packed convert (RNE, identical to f2bf)
#pragma unroll
      for (int m = 0; m < 4; ++m) {
        pk[ctq][m][0] = cvt_pk_bf16(s[ctq][m][0], s[ctq][m][1]);
        pk[ctq][m][1] = cvt_pk_bf16(s[ctq][m][2], s[ctq][m][3]);
      }
    }

    // redistribute P (C layout) -> B-frag layout via permlane swaps
    // (32-swap then 16-swap; element-movement order verified, v11-proven).
    bf16x8 pb[2][2];
#pragma unroll
    for (int ctq = 0; ctq < 2; ++ctq)
#pragma unroll
      for (int c = 0; c < 2; ++c) {
        unsigned int a  = pk[ctq][2 * c][0];
        unsigned int bb = pk[ctq][2 * c][1];
        unsigned int cc = pk[ctq][2 * c + 1][0];
        unsigned int d  = pk[ctq][2 * c + 1][1];
        asm("v_permlane32_swap_b32 %0, %1" : "+v"(a),  "+v"(cc));
        asm("v_permlane32_swap_b32 %0, %1" : "+v"(bb), "+v"(d));
        asm("v_permlane16_swap_b32 %0, %1" : "+v"(a),  "+v"(cc));
        asm("v_permlane16_swap_b32 %0, %1" : "+v"(bb), "+v"(d));
        u32x4 w;
        w[0] = a; w[1] = bb; w[2] = cc; w[3] = d;
        pb[ctq][c] = __builtin_bit_cast(bf16x8, w);
      }

    // O^T += V^T · P from LDS
    __builtin_amdgcn_s_setprio(1);
#pragma unroll
    for (int ht = 0; ht < 8; ++ht)
#pragma unroll
      for (int c = 0; c < 2; ++c) {
        bf16x8 vf = vls[cur][(ht * 2 + c) * 64 + lane];
#pragma unroll
        for (int ctq = 0; ctq < 2; ++ctq)
          o_acc[ht][ctq] = mfma16(vf, pb[ctq][c], o_acc[ht][ctq]);
      }
    __builtin_amdgcn_s_setprio(0);

    __syncthreads();   // single barrier per tile
    cur ^= 1;
    bc0 = bn0;
    bc1 = bn1;
  }

  // epilogue: normalize, store bf16. O^T frag: row h = ht*16+qq*4+r, col q=hh.
#pragma unroll
  for (int ctq = 0; ctq < 2; ++ctq) {
    float inv = 1.0f / l_run[ctq];
    const long row = qbase + ctq * 16 + hh;
#pragma unroll
    for (int ht = 0; ht < 8; ++ht) {
      f32x4 o = o_acc[ht][ctq];
      uint2 w;
      w.x = cvt_pk_bf16(o[0] * inv, o[1] * inv);
      w.y = cvt_pk_bf16(o[2] * inv, o[3] * inv);
      *(uint2*)(out_att + row * 128 + ht * 16 + qq * 4) = w;
    }
  }
}

// ---------------------------------------------------------------------------
// Kernel 3: out = relu(out_att @ Wout + bout) fused with the three heads.
// ---------------------------------------------------------------------------
__global__ __launch_bounds__(256) void wout_heads_kernel(
    const unsigned short* __restrict__ out_att, const unsigned short* __restrict__ WoutT,
    const float* __restrict__ bout,
    const float* __restrict__ Wval, const float* __restrict__ bval,
    const float* __restrict__ Wadv1, const float* __restrict__ badv1,
    const float* __restrict__ Wadv2, const float* __restrict__ badv2,
    float* __restrict__ value, float* __restrict__ adv1, float* __restrict__ adv2) {
  const int lane = threadIdx.x & 63, wid = threadIdx.x >> 6;
  const int qq = lane >> 4, hh = lane & 15;
  const long rowA = (long)blockIdx.x * 64 + wid * 16 + hh;
  const f32x4 zero4 = {0.f, 0.f, 0.f, 0.f};
  f32x4 acc[8];
#pragma unroll
  for (int t = 0; t < 8; ++t) acc[t] = zero4;
#pragma unroll
  for (int kc = 0; kc < 4; ++kc) {
    bf16x8 af = *(const bf16x8*)(out_att + rowA * 128 + kc * 32 + qq * 8);
#pragma unroll
    for (int t = 0; t < 8; ++t) {
      bf16x8 bf = *(const bf16x8*)(WoutT + (t * 16 + hh) * 128 + kc * 32 + qq * 8);
      acc[t] = mfma16(af, bf, acc[t]);
    }
  }
  float pv[4] = {0.f, 0.f, 0.f, 0.f};
  float pa1[4][8], pa2[4][8];
#pragma unroll
  for (int r = 0; r < 4; ++r)
#pragma unroll
    for (int j = 0; j < 8; ++j) { pa1[r][j] = 0.f; pa2[r][j] = 0.f; }
#pragma unroll
  for (int t = 0; t < 8; ++t) {
    const int col = t * 16 + hh;
    const float bo = bout[col];
    const float wv = Wval[col];
    const f32x4 w1a = *(const f32x4*)(Wadv1 + col * 8);
    const f32x4 w1b = *(const f32x4*)(Wadv1 + col * 8 + 4);
    const f32x4 w2a = *(const f32x4*)(Wadv2 + col * 8);
    const f32x4 w2b = *(const f32x4*)(Wadv2 + col * 8 + 4);
#pragma unroll
    for (int r = 0; r < 4; ++r) {
      float h = fmaxf(acc[t][r] + bo, 0.f);
      pv[r] += h * wv;
#pragma unroll
      for (int j = 0; j < 4; ++j) {
        pa1[r][j]     += h * w1a[j];
        pa1[r][4 + j] += h * w1b[j];
        pa2[r][j]     += h * w2a[j];
        pa2[r][4 + j] += h * w2b[j];
      }
    }
  }
#pragma unroll
  for (int r = 0; r < 4; ++r) {
#pragma unroll
    for (int s = 1; s < 16; s <<= 1) {
      pv[r] += __shfl_xor(pv[r], s, 64);
#pragma unroll
      for (int j = 0; j < 8; ++j) {
        pa1[r][j] += __shfl_xor(pa1[r][j], s, 64);
        pa2[r][j] += __shfl_xor(pa2[r][j], s, 64);
      }
    }
  }
  if (hh == 0) {
    const float bv0 = bval[0];
#pragma unroll
    for (int r = 0; r < 4; ++r) {
      const long row = (long)blockIdx.x * 64 + wid * 16 + qq * 4 + r;
      value[row] = pv[r] + bv0;
#pragma unroll
      for (int j = 0; j < 8; ++j) {
        adv1[row * 8 + j] = pa1[r][j] + badv1[j];
        adv2[row * 8 + j] = pa2[r][j] + badv2[j];
      }
    }
  }
}

// ---------------------------------------------------------------------------
// Kernel 4: FUSED sums + combine (v12-proven). 256 blocks (8 per batch);
// redundant deterministic sums, then each block writes its 1/8 slice.
// ---------------------------------------------------------------------------
__global__ __launch_bounds__(256) void combine_kernel(
    const float* __restrict__ value, const float* __restrict__ adv1,
    const float* __restrict__ adv2, float* __restrict__ out) {
  const int b = blockIdx.x >> 3;
  const int slice = blockIdx.x & 7;
  const int tid = threadIdx.x;
  __shared__ float red[4][16];

  float p[16];
#pragma unroll
  for (int j = 0; j < 16; ++j) p[j] = 0.f;
  for (int n = tid; n < 2048; n += 256) {
    const long row = (long)b * 2048 + n;
    const f32x4 a1a = *(const f32x4*)(adv1 + row * 8);
    const f32x4 a1b = *(const f32x4*)(adv1 + row * 8 + 4);
    const f32x4 a2a = *(const f32x4*)(adv2 + row * 8);
    const f32x4 a2b = *(const f32x4*)(adv2 + row * 8 + 4);
#pragma unroll
    for (int j = 0; j < 4; ++j) {
      p[j] += a1a[j]; p[4 + j] += a1b[j];
      p[8 + j] += a2a[j]; p[12 + j] += a2b[j];
    }
  }
#pragma unroll
  for (int s = 1; s < 64; s <<= 1)
#pragma unroll
    for (int j = 0; j < 16; ++j) p[j] += __shfl_xor(p[j], s, 64);
  const int wid = tid >> 6;
  if ((tid & 63) == 0)
#pragma unroll
    for (int j = 0; j < 16; ++j) red[wid][j] = p[j];
  __syncthreads();

  float mean1[8], mean2[8];
#pragma unroll
  for (int j = 0; j < 8; ++j) {
    mean1[j] = (red[0][j] + red[1][j] + red[2][j] + red[3][j]) * (1.0f / 2048.0f);
    mean2[j] = (red[0][8 + j] + red[1][8 + j] + red[2][8 + j] + red[3][8 + j]) * (1.0f / 2048.0f);
  }

  const int n = slice * 256 + tid;
  const long row = (long)b * 2048 + n;
  const float v = value[row];
  const f32x4 a1a = *(const f32x4*)(adv1 + row * 8);
  const f32x4 a1b = *(const f32x4*)(adv1 + row * 8 + 4);
  const f32x4 a2a = *(const f32x4*)(adv2 + row * 8);
  const f32x4 a2b = *(const f32x4*)(adv2 + row * 8 + 4);
  f32x4 o1a, o1b, o2a, o2b;
#pragma unroll
  for (int j = 0; j < 4; ++j) {
    o1a[j] = v + a1a[j] - mean1[j];
    o1b[j] = v + a1b[j] - mean1[4 + j];
    o2a[j] = v + a2a[j] - mean2[j];
    o2b[j] = v + a2b[j] - mean2[4 + j];
  }
  *(f32x4*)(out + row * 8) = o1a;
  *(f32x4*)(out + row * 8 + 4) = o1b;
  *(f32x4*)(out + 524288 + row * 8) = o2a;
  *(f32x4*)(out + 524288 + row * 8 + 4) = o2b;
}

// ---------------------------------------------------------------------------
extern "C" void kernel_launch(void* const* d_in, const int* in_sizes, int n_in,
                              void* d_out, int out_size, void* d_ws, size_t ws_size,
                              hipStream_t stream) {
  const float* x     = (const float*)d_in[0];
  const float* mask  = (const float*)d_in[1];
  const float* Wv    = (const float*)d_in[2];
  const float* bv    = (const float*)d_in[3];
  const float* Wk    = (const float*)d_in[4];
  const float* bk    = (const float*)d_in[5];
  const float* Wq    = (const float*)d_in[6];
  const float* bq    = (const float*)d_in[7];
  const float* Wout  = (const float*)d_in[8];
  const float* bout  = (const float*)d_in[9];
  const float* Wval  = (const float*)d_in[10];
  const float* bval  = (const float*)d_in[11];
  const float* Wadv1 = (const float*)d_in[12];
  const float* badv1 = (const float*)d_in[13];
  const float* Wadv2 = (const float*)d_in[14];
  const float* badv2 = (const float*)d_in[15];
  float* out = (float*)d_out;
  char* ws = (char*)d_ws;

  // workspace layout (bytes)
  unsigned short* q_bf   = (unsigned short*)(ws + 0);          // 16 MB
  unsigned short* Kf     = (unsigned short*)(ws + 16777216);   // 16 MB
  unsigned short* Vf     = (unsigned short*)(ws + 33554432);   // 16 MB
  unsigned short* out_at = (unsigned short*)(ws + 50331648);   // 16 MB
  float* value = (float*)(ws + 67108864);                      // 256 KB
  float* adv1  = (float*)(ws + 67371008);                      // 2 MB
  float* adv2  = (float*)(ws + 69468160);                      // 2 MB
  unsigned short* Wf_hi = (unsigned short*)(ws + 71567360);    // 192 KB
  unsigned short* Wf_lo = (unsigned short*)(ws + 71763968);    // 192 KB
  unsigned short* WoutT = (unsigned short*)(ws + 71960576);    // 32 KB
  unsigned long long* bits = (unsigned long long*)(ws + 71993344);  // 16 MB

  prepack_kernel<<<2160, 256, 0, stream>>>(mask, bits, Wv, Wk, Wq, Wout,
                                           Wf_hi, Wf_lo, WoutT);
  proj_kernel<<<1024, 256, 0, stream>>>(x, Wf_hi, Wf_lo, bq, bk, bv, q_bf, Kf, Vf);
  attn_kernel<<<512, 256, 0, stream>>>(q_bf, Kf, Vf, bits, out_at);
  wout_heads_kernel<<<1024, 256, 0, stream>>>(out_at, WoutT, bout, Wval, bval,
                                              Wadv1, badv1, Wadv2, badv2,
                                              value, adv1, adv2);
  combine_kernel<<<256, 256, 0, stream>>>(value, adv1, adv2, out);
}